// Round 1
// baseline (1997.355 us; speedup 1.0000x reference)
//
#include <hip/hip_runtime.h>
#include <math.h>

#define BB 2
#define TT 2048
#define DD 1024
#define NH 16
#define NKV 4
#define HD 64
#define GG 4
#define EPSF 1.1920929e-07f
// T=2048 > TSL=1024 -> nb = 10000 * 2^(64/62); log2(nb) = log2(1e4) + 64/62
#define LOG2_NB 14.319970444065578

// ---------------- QKV projection GEMM: C[m][n] = dot(x[m,:], W[n,:]) ----------------
// M=4096, K=1024, N=1536 (q:0..1023 -> qw, k:1024..1279 -> kw, v:1280..1535 -> vw + ve)
__global__ __launch_bounds__(256) void gemm_qkv(
    const float* __restrict__ x, const float* __restrict__ qw,
    const float* __restrict__ kw, const float* __restrict__ vw,
    const float* __restrict__ ve, float* __restrict__ qkv)
{
    __shared__ float As[64][20];
    __shared__ float Bs[64][20];
    int tid = threadIdx.x;
    int tx = tid & 15, ty = tid >> 4;
    int m0 = blockIdx.y * 64, n0 = blockIdx.x * 64;
    int lr = tid >> 2, lc = (tid & 3) * 4;
    int nload = n0 + lr;
    const float* brow;
    if (nload < 1024)      brow = qw + (size_t)nload * 1024;
    else if (nload < 1280) brow = kw + (size_t)(nload - 1024) * 1024;
    else                   brow = vw + (size_t)(nload - 1280) * 1024;
    const float* arow = x + (size_t)(m0 + lr) * 1024;
    float acc[4][4] = {};
    for (int k0 = 0; k0 < 1024; k0 += 16) {
        float4 av = *(const float4*)(arow + k0 + lc);
        float4 bv = *(const float4*)(brow + k0 + lc);
        *(float4*)&As[lr][lc] = av;
        *(float4*)&Bs[lr][lc] = bv;
        __syncthreads();
        #pragma unroll
        for (int kk = 0; kk < 16; kk += 4) {
            float4 a4[4], b4[4];
            #pragma unroll
            for (int i = 0; i < 4; i++) a4[i] = *(const float4*)&As[ty*4+i][kk];
            #pragma unroll
            for (int j = 0; j < 4; j++) b4[j] = *(const float4*)&Bs[tx*4+j][kk];
            #pragma unroll
            for (int i = 0; i < 4; i++)
                #pragma unroll
                for (int j = 0; j < 4; j++)
                    acc[i][j] += a4[i].x*b4[j].x + a4[i].y*b4[j].y
                               + a4[i].z*b4[j].z + a4[i].w*b4[j].w;
        }
        __syncthreads();
    }
    #pragma unroll
    for (int i = 0; i < 4; i++) {
        int m = m0 + ty*4 + i;
        #pragma unroll
        for (int j = 0; j < 4; j++) {
            int nn = n0 + tx*4 + j;
            float v = acc[i][j];
            if (nn >= 1280) v += ve[(size_t)m*256 + (nn - 1280)];
            qkv[(size_t)m*1536 + nn] = v;
        }
    }
}

// ---------------- out projection GEMM: out[m][n] = dot(y[m,:], ow[n,:]) ----------------
__global__ __launch_bounds__(256) void gemm_out(
    const float* __restrict__ y, const float* __restrict__ ow, float* __restrict__ out)
{
    __shared__ float As[64][20];
    __shared__ float Bs[64][20];
    int tid = threadIdx.x;
    int tx = tid & 15, ty = tid >> 4;
    int m0 = blockIdx.y * 64, n0 = blockIdx.x * 64;
    int lr = tid >> 2, lc = (tid & 3) * 4;
    const float* brow = ow + (size_t)(n0 + lr) * 1024;
    const float* arow = y + (size_t)(m0 + lr) * 1024;
    float acc[4][4] = {};
    for (int k0 = 0; k0 < 1024; k0 += 16) {
        float4 av = *(const float4*)(arow + k0 + lc);
        float4 bv = *(const float4*)(brow + k0 + lc);
        *(float4*)&As[lr][lc] = av;
        *(float4*)&Bs[lr][lc] = bv;
        __syncthreads();
        #pragma unroll
        for (int kk = 0; kk < 16; kk += 4) {
            float4 a4[4], b4[4];
            #pragma unroll
            for (int i = 0; i < 4; i++) a4[i] = *(const float4*)&As[ty*4+i][kk];
            #pragma unroll
            for (int j = 0; j < 4; j++) b4[j] = *(const float4*)&Bs[tx*4+j][kk];
            #pragma unroll
            for (int i = 0; i < 4; i++)
                #pragma unroll
                for (int j = 0; j < 4; j++)
                    acc[i][j] += a4[i].x*b4[j].x + a4[i].y*b4[j].y
                               + a4[i].z*b4[j].z + a4[i].w*b4[j].w;
        }
        __syncthreads();
    }
    #pragma unroll
    for (int i = 0; i < 4; i++) {
        int m = m0 + ty*4 + i;
        #pragma unroll
        for (int j = 0; j < 4; j++)
            out[(size_t)m*1024 + n0 + tx*4 + j] = acc[i][j];
    }
}

// ---------------- per-head epilogue: RMSNorm + RoPE + gain (q,k), v mix + raw_v ----------------
// one wave (64 lanes = HD) per (row, head-task); 24 tasks per row (16 q + 4 k + 4 v)
__global__ __launch_bounds__(256) void qkv_epilogue(
    const float* __restrict__ qkv, const float* __restrict__ v0,
    const float* __restrict__ q_gain, const float* __restrict__ vr_lambda,
    float* __restrict__ qb, float* __restrict__ kb, float* __restrict__ vb,
    float* __restrict__ rawv)
{
    int wave = blockIdx.x * 4 + (threadIdx.x >> 6);
    int lane = threadIdx.x & 63;
    int row = wave / 24;     // 0..4095  (b*T + t)
    int hh  = wave % 24;
    int t = row & (TT - 1);

    if (hh < 20) {
        // q head (hh<16) or k head (hh-16)
        int col = (hh < 16) ? (hh*64 + lane) : (1024 + (hh-16)*64 + lane);
        float val = qkv[(size_t)row*1536 + col];
        float ss = val * val;
        #pragma unroll
        for (int off = 32; off; off >>= 1) ss += __shfl_xor(ss, off);
        val *= rsqrtf(ss * (1.0f/64.0f) + EPSF);
        float partner = __shfl(val, lane ^ 32);
        int idx = lane & 31;
        float inv = (float)exp2((double)idx * (-LOG2_NB / 32.0));
        float fr = (float)t * inv;
        float sn, cs;
        sincosf(fr, &sn, &cs);
        float outv = (lane < 32) ? (val*cs + partner*sn) : (val*cs - partner*sn);
        if (hh < 16) {
            outv *= q_gain[hh];
            qb[((size_t)row*16 + hh)*64 + lane] = outv;
        } else {
            kb[((size_t)row*4 + (hh-16))*64 + lane] = outv;
        }
    } else {
        int vh = hh - 20;
        size_t off = ((size_t)row*4 + vh)*64 + lane;
        float vraw = qkv[(size_t)row*1536 + 1280 + vh*64 + lane];
        rawv[off] = vraw;
        vb[off] = vr_lambda[0]*v0[off] + vr_lambda[1]*vraw;
    }
}

// ---------------- gate: sigmoid(x @ gate_w.T + gate_b) ----------------
__global__ __launch_bounds__(256) void gate_kernel(
    const float* __restrict__ x, const float* __restrict__ gw,
    const float* __restrict__ gb, float* __restrict__ gate)
{
    __shared__ float xs[1024];
    int row = blockIdx.x;
    int tid = threadIdx.x;
    *(float4*)&xs[tid*4] = *(const float4*)&x[(size_t)row*1024 + tid*4];
    __syncthreads();
    int wave = tid >> 6, lane = tid & 63;
    for (int h = wave; h < 16; h += 4) {
        const float* w = gw + (size_t)h * 1024;
        float s = 0.f;
        #pragma unroll
        for (int i = 0; i < 16; i++) s += xs[lane + 64*i] * w[lane + 64*i];
        #pragma unroll
        for (int off = 32; off; off >>= 1) s += __shfl_xor(s, off);
        if (lane == 0) gate[(size_t)row*16 + h] = 1.0f / (1.0f + __expf(-(s + gb[h])));
    }
}

// ---------------- flash attention (causal, GQA) ----------------
// block = 256 threads: 64 q rows x 4 g-heads sharing one kv head; K/V tiles of 64 in LDS
__global__ __launch_bounds__(256, 1) void flash(
    const float* __restrict__ qb, const float* __restrict__ kb,
    const float* __restrict__ vb, const float* __restrict__ gate,
    float* __restrict__ y)
{
    __shared__ float Ks[64][64];
    __shared__ float Vs[64][64];
    int b = blockIdx.x >> 2, kvh = blockIdx.x & 3;
    int qt = blockIdx.y;
    int tid = threadIdx.x;
    int qr = tid & 63, g = tid >> 6;
    int h = kvh*4 + g;
    int qrow = qt*64 + qr;
    int grow = b*TT + qrow;

    float4 qv[16], o[16];
    const float4* qp = (const float4*)(qb + ((size_t)grow*16 + h)*64);
    #pragma unroll
    for (int i = 0; i < 16; i++) { qv[i] = qp[i]; o[i] = make_float4(0.f,0.f,0.f,0.f); }
    float m = -INFINITY, l = 0.0f;
    const float scale = 0.125f;  // 1/sqrt(64)

    for (int kt = 0; kt <= qt; kt++) {
        #pragma unroll
        for (int i = 0; i < 4; i++) {
            int f = tid + i*256;         // float4 index 0..1023
            int r = f >> 4, c = (f & 15) * 4;
            size_t src = ((size_t)(b*TT + kt*64 + r)*4 + kvh)*64 + c;
            *(float4*)&Ks[r][c] = *(const float4*)&kb[src];
            *(float4*)&Vs[r][c] = *(const float4*)&vb[src];
        }
        __syncthreads();
        int jmax = (kt == qt) ? qr : 63;
        for (int j = 0; j <= jmax; j++) {
            const float4* kr = (const float4*)&Ks[j][0];
            float s = 0.f;
            #pragma unroll
            for (int i = 0; i < 16; i++) {
                float4 kk = kr[i];
                s += qv[i].x*kk.x + qv[i].y*kk.y + qv[i].z*kk.z + qv[i].w*kk.w;
            }
            s *= scale;
            if (s > m) {
                float c = __expf(m - s);   // exp(-inf)=0 handles first iter
                l *= c;
                #pragma unroll
                for (int i = 0; i < 16; i++) {
                    o[i].x*=c; o[i].y*=c; o[i].z*=c; o[i].w*=c;
                }
                m = s;
            }
            float p = __expf(s - m);
            l += p;
            const float4* vr = (const float4*)&Vs[j][0];
            #pragma unroll
            for (int i = 0; i < 16; i++) {
                float4 vv = vr[i];
                o[i].x += p*vv.x; o[i].y += p*vv.y; o[i].z += p*vv.z; o[i].w += p*vv.w;
            }
        }
        __syncthreads();
    }
    float gv = gate[(size_t)grow*16 + h] / l;
    float4* yp = (float4*)(y + (size_t)grow*1024 + h*64);
    #pragma unroll
    for (int i = 0; i < 16; i++)
        yp[i] = make_float4(o[i].x*gv, o[i].y*gv, o[i].z*gv, o[i].w*gv);
}

extern "C" void kernel_launch(void* const* d_in, const int* in_sizes, int n_in,
                              void* d_out, int out_size, void* d_ws, size_t ws_size,
                              hipStream_t stream) {
    (void)in_sizes; (void)n_in; (void)out_size; (void)ws_size;
    const float* x  = (const float*)d_in[0];
    const float* qw = (const float*)d_in[1];
    const float* kw = (const float*)d_in[2];
    const float* vw = (const float*)d_in[3];
    const float* ow = (const float*)d_in[4];
    const float* ve = (const float*)d_in[5];
    const float* v0 = (const float*)d_in[6];
    const float* qg = (const float*)d_in[7];
    const float* vl = (const float*)d_in[8];
    const float* gw = (const float*)d_in[9];
    const float* gb = (const float*)d_in[10];

    float* out  = (float*)d_out;
    float* rawv = out + (size_t)BB*TT*DD;          // second output

    float* ws  = (float*)d_ws;
    float* qkv = ws;                                // 4096*1536
    float* qb  = ws + 6291456;                      // 4096*1024
    float* kb  = qb + 4194304;                      // 4096*256
    float* vb  = kb + 1048576;                      // 4096*256
    float* gt  = vb + 1048576;                      // 4096*16
    float* y   = qkv;                               // reuse qkv region after epilogue

    gemm_qkv<<<dim3(24, 64), 256, 0, stream>>>(x, qw, kw, vw, ve, qkv);
    qkv_epilogue<<<24576, 256, 0, stream>>>(qkv, v0, qg, vl, qb, kb, vb, rawv);
    gate_kernel<<<4096, 256, 0, stream>>>(x, gw, gb, gt);
    flash<<<dim3(8, 32), 256, 0, stream>>>(qb, kb, vb, gt, y);
    gemm_out<<<dim3(16, 64), 256, 0, stream>>>(y, ow, out);
}

// Round 2
// 713.656 us; speedup vs baseline: 2.7988x; 2.7988x over previous
//
#include <hip/hip_runtime.h>
#include <math.h>

#define BB 2
#define TT 2048
#define DD 1024
#define NH 16
#define NKV 4
#define HD 64
#define EPSF 1.1920929e-07f
// T=2048 > TSL=1024 -> nb = 10000 * 2^(64/62); log2(nb) = log2(1e4) + 64/62
#define LOG2_NB 14.319970444065578

typedef __attribute__((ext_vector_type(8))) short bf16x8;
typedef __attribute__((ext_vector_type(4))) float f32x4;

__device__ inline short f2bf(float f) {
    unsigned u = __builtin_bit_cast(unsigned, f);
    unsigned r = (u + 0x7fffu + ((u >> 16) & 1u)) >> 16;
    return (short)r;
}

// ---------------- QKV projection GEMM (fp32): C[m][n] = dot(x[m,:], W[n,:]) ----------------
__global__ __launch_bounds__(256) void gemm_qkv(
    const float* __restrict__ x, const float* __restrict__ qw,
    const float* __restrict__ kw, const float* __restrict__ vw,
    const float* __restrict__ ve, float* __restrict__ qkv)
{
    __shared__ float As[64][20];
    __shared__ float Bs[64][20];
    int tid = threadIdx.x;
    int tx = tid & 15, ty = tid >> 4;
    int m0 = blockIdx.y * 64, n0 = blockIdx.x * 64;
    int lr = tid >> 2, lc = (tid & 3) * 4;
    int nload = n0 + lr;
    const float* brow;
    if (nload < 1024)      brow = qw + (size_t)nload * 1024;
    else if (nload < 1280) brow = kw + (size_t)(nload - 1024) * 1024;
    else                   brow = vw + (size_t)(nload - 1280) * 1024;
    const float* arow = x + (size_t)(m0 + lr) * 1024;
    float acc[4][4] = {};
    for (int k0 = 0; k0 < 1024; k0 += 16) {
        float4 av = *(const float4*)(arow + k0 + lc);
        float4 bv = *(const float4*)(brow + k0 + lc);
        *(float4*)&As[lr][lc] = av;
        *(float4*)&Bs[lr][lc] = bv;
        __syncthreads();
        #pragma unroll
        for (int kk = 0; kk < 16; kk += 4) {
            float4 a4[4], b4[4];
            #pragma unroll
            for (int i = 0; i < 4; i++) a4[i] = *(const float4*)&As[ty*4+i][kk];
            #pragma unroll
            for (int j = 0; j < 4; j++) b4[j] = *(const float4*)&Bs[tx*4+j][kk];
            #pragma unroll
            for (int i = 0; i < 4; i++)
                #pragma unroll
                for (int j = 0; j < 4; j++)
                    acc[i][j] += a4[i].x*b4[j].x + a4[i].y*b4[j].y
                               + a4[i].z*b4[j].z + a4[i].w*b4[j].w;
        }
        __syncthreads();
    }
    #pragma unroll
    for (int i = 0; i < 4; i++) {
        int m = m0 + ty*4 + i;
        #pragma unroll
        for (int j = 0; j < 4; j++) {
            int nn = n0 + tx*4 + j;
            float v = acc[i][j];
            if (nn >= 1280) v += ve[(size_t)m*256 + (nn - 1280)];
            qkv[(size_t)m*1536 + nn] = v;
        }
    }
}

// ---------------- out projection GEMM (fp32) ----------------
__global__ __launch_bounds__(256) void gemm_out(
    const float* __restrict__ y, const float* __restrict__ ow, float* __restrict__ out)
{
    __shared__ float As[64][20];
    __shared__ float Bs[64][20];
    int tid = threadIdx.x;
    int tx = tid & 15, ty = tid >> 4;
    int m0 = blockIdx.y * 64, n0 = blockIdx.x * 64;
    int lr = tid >> 2, lc = (tid & 3) * 4;
    const float* brow = ow + (size_t)(n0 + lr) * 1024;
    const float* arow = y + (size_t)(m0 + lr) * 1024;
    float acc[4][4] = {};
    for (int k0 = 0; k0 < 1024; k0 += 16) {
        float4 av = *(const float4*)(arow + k0 + lc);
        float4 bv = *(const float4*)(brow + k0 + lc);
        *(float4*)&As[lr][lc] = av;
        *(float4*)&Bs[lr][lc] = bv;
        __syncthreads();
        #pragma unroll
        for (int kk = 0; kk < 16; kk += 4) {
            float4 a4[4], b4[4];
            #pragma unroll
            for (int i = 0; i < 4; i++) a4[i] = *(const float4*)&As[ty*4+i][kk];
            #pragma unroll
            for (int j = 0; j < 4; j++) b4[j] = *(const float4*)&Bs[tx*4+j][kk];
            #pragma unroll
            for (int i = 0; i < 4; i++)
                #pragma unroll
                for (int j = 0; j < 4; j++)
                    acc[i][j] += a4[i].x*b4[j].x + a4[i].y*b4[j].y
                               + a4[i].z*b4[j].z + a4[i].w*b4[j].w;
        }
        __syncthreads();
    }
    #pragma unroll
    for (int i = 0; i < 4; i++) {
        int m = m0 + ty*4 + i;
        #pragma unroll
        for (int j = 0; j < 4; j++)
            out[(size_t)m*1024 + n0 + tx*4 + j] = acc[i][j];
    }
}

// ---------------- epilogue: RMSNorm + RoPE + gain (q,k) -> bf16; v mix -> bf16 V^T; raw_v fp32 ----------------
// one wave per (row, task); 24 tasks per row (16 q + 4 k + 4 v)
__global__ __launch_bounds__(256) void qkv_epilogue(
    const float* __restrict__ qkv, const float* __restrict__ v0,
    const float* __restrict__ q_gain, const float* __restrict__ vr_lambda,
    short* __restrict__ qbh, short* __restrict__ kbh, short* __restrict__ vtb,
    float* __restrict__ rawv)
{
    int wave = blockIdx.x * 4 + (threadIdx.x >> 6);
    int lane = threadIdx.x & 63;
    int row = wave / 24;     // 0..4095  (b*T + t)
    int hh  = wave % 24;
    int b = row >> 11;
    int t = row & (TT - 1);

    if (hh < 20) {
        int col = (hh < 16) ? (hh*64 + lane) : (1024 + (hh-16)*64 + lane);
        float val = qkv[(size_t)row*1536 + col];
        float ss = val * val;
        #pragma unroll
        for (int off = 32; off; off >>= 1) ss += __shfl_xor(ss, off);
        val *= rsqrtf(ss * (1.0f/64.0f) + EPSF);
        float partner = __shfl(val, lane ^ 32);
        int idx = lane & 31;
        float inv = (float)exp2((double)idx * (-LOG2_NB / 32.0));
        float fr = (float)t * inv;
        float sn, cs;
        sincosf(fr, &sn, &cs);
        float outv = (lane < 32) ? (val*cs + partner*sn) : (val*cs - partner*sn);
        if (hh < 16) {
            outv *= q_gain[hh];
            qbh[(((size_t)(b*16 + hh))*2048 + t)*64 + lane] = f2bf(outv);
        } else {
            kbh[(((size_t)(b*4 + (hh-16)))*2048 + t)*64 + lane] = f2bf(outv);
        }
    } else {
        int vh = hh - 20;
        size_t off = ((size_t)row*4 + vh)*64 + lane;
        float vraw = qkv[(size_t)row*1536 + 1280 + vh*64 + lane];
        rawv[off] = vraw;
        float vmix = vr_lambda[0]*v0[off] + vr_lambda[1]*vraw;
        // V^T: [b][kvh][d=lane][t]
        vtb[(((size_t)(b*4 + vh))*64 + lane)*2048 + t] = f2bf(vmix);
    }
}

// ---------------- gate: sigmoid(x @ gate_w.T + gate_b) ----------------
__global__ __launch_bounds__(256) void gate_kernel(
    const float* __restrict__ x, const float* __restrict__ gw,
    const float* __restrict__ gb, float* __restrict__ gate)
{
    __shared__ float xs[1024];
    int row = blockIdx.x;
    int tid = threadIdx.x;
    *(float4*)&xs[tid*4] = *(const float4*)&x[(size_t)row*1024 + tid*4];
    __syncthreads();
    int wave = tid >> 6, lane = tid & 63;
    for (int h = wave; h < 16; h += 4) {
        const float* w = gw + (size_t)h * 1024;
        float s = 0.f;
        #pragma unroll
        for (int i = 0; i < 16; i++) s += xs[lane + 64*i] * w[lane + 64*i];
        #pragma unroll
        for (int off = 32; off; off >>= 1) s += __shfl_xor(s, off);
        if (lane == 0) gate[(size_t)row*16 + h] = 1.0f / (1.0f + __expf(-(s + gb[h])));
    }
}

// ---------------- MFMA flash attention (bf16 inputs, fp32 accumulate) ----------------
// block = 256 threads = 4 waves; block handles (b, h, 64-q-row tile); wave w owns 16 q rows.
// K tile [key][d] and V^T tile [d][key] staged to LDS via global_load_lds (8KB each, bf16).
#define PS_LD 72   // Ps row stride in shorts (144B: 16B-aligned frag reads)
__global__ __launch_bounds__(256) void flash_mfma(
    const short* __restrict__ qbh, const short* __restrict__ kbh,
    const short* __restrict__ vtb, const float* __restrict__ gate,
    float* __restrict__ y)
{
    __shared__ short Ks[64*64];
    __shared__ short Vt[64*64];
    __shared__ short Ps[4][16*PS_LD];

    int bh = blockIdx.x;             // b*16 + h
    int b = bh >> 4, h = bh & 15, kvh = h >> 2;
    int qt = blockIdx.y;
    int tid = threadIdx.x;
    int w = tid >> 6, lane = tid & 63;
    int quad = lane >> 4, lc = lane & 15;

    // Q A-fragments (16 q rows x 64 d), loaded straight from global (contiguous 16B/lane)
    const short* qbase = qbh + (((size_t)bh)*2048 + qt*64 + w*16 + lc)*64;
    bf16x8 qf0 = *(const bf16x8*)(qbase + quad*8);
    bf16x8 qf1 = *(const bf16x8*)(qbase + 32 + quad*8);

    f32x4 o[4];
    #pragma unroll
    for (int i = 0; i < 4; i++) o[i] = (f32x4){0.f,0.f,0.f,0.f};
    float m_r[4], l_r[4];
    #pragma unroll
    for (int r = 0; r < 4; r++) { m_r[r] = -1e30f; l_r[r] = 0.f; }
    const float scale = 0.125f;

    const size_t ktile_base = (((size_t)(b*4 + kvh))*2048) * 64;   // element base of K [t][d]
    const size_t vrow_base  = (((size_t)(b*4 + kvh))*64) * 2048;   // element base of V^T [d][t]

    for (int kt = 0; kt <= qt; kt++) {
        __syncthreads();   // everyone done reading previous tile
        // ---- stage K tile: 8KB contiguous global -> flat LDS; each wave 2x1KB
        #pragma unroll
        for (int i = 0; i < 2; i++) {
            int off = w*2048 + i*1024;                    // byte offset, wave-uniform
            const short* gp = kbh + ktile_base + (size_t)(kt*64)*64 + (off + lane*16)/2;
            __builtin_amdgcn_global_load_lds(
                (const __attribute__((address_space(1))) void*)gp,
                (__attribute__((address_space(3))) void*)((char*)Ks + off), 16, 0, 0);
        }
        // ---- stage V^T tile: 64 rows (d) x 128B from strided global -> flat LDS
        #pragma unroll
        for (int i = 0; i < 2; i++) {
            int off = w*2048 + i*1024;                    // byte offset, wave-uniform
            int f = off + lane*16;
            int d = f >> 7, cb = f & 127;                 // row, byte within row
            const short* gp = vtb + vrow_base + (size_t)d*2048 + kt*64 + cb/2;
            __builtin_amdgcn_global_load_lds(
                (const __attribute__((address_space(1))) void*)gp,
                (__attribute__((address_space(3))) void*)((char*)Vt + off), 16, 0, 0);
        }
        __syncthreads();   // DMA drained (vmcnt(0) before barrier)

        // ---- S = Q K^T : 4 key-blocks of 16, each 2 MFMAs over d=64
        f32x4 s4[4];
        #pragma unroll
        for (int kn = 0; kn < 4; kn++) {
            const short* kr = Ks + (kn*16 + lc)*64;
            bf16x8 kf0 = *(const bf16x8*)(kr + quad*8);
            bf16x8 kf1 = *(const bf16x8*)(kr + 32 + quad*8);
            f32x4 acc = (f32x4){0.f,0.f,0.f,0.f};
            acc = __builtin_amdgcn_mfma_f32_16x16x32_bf16(qf0, kf0, acc, 0, 0, 0);
            acc = __builtin_amdgcn_mfma_f32_16x16x32_bf16(qf1, kf1, acc, 0, 0, 0);
            s4[kn] = acc;
        }

        // ---- online softmax in C-layout: lane holds rows quad*4+r, col = kn*16+lc
        bool diag = (kt == qt);
        float sv[4][4];   // [kn][r]
        #pragma unroll
        for (int kn = 0; kn < 4; kn++)
            #pragma unroll
            for (int r = 0; r < 4; r++) {
                float s = s4[kn][r] * scale;
                if (diag && (kn*16 + lc > w*16 + quad*4 + r)) s = -1e30f;
                sv[kn][r] = s;
            }
        float alpha[4];
        #pragma unroll
        for (int r = 0; r < 4; r++) {
            float mn = fmaxf(fmaxf(sv[0][r], sv[1][r]), fmaxf(sv[2][r], sv[3][r]));
            #pragma unroll
            for (int off = 1; off < 16; off <<= 1) mn = fmaxf(mn, __shfl_xor(mn, off));
            mn = fmaxf(mn, m_r[r]);
            alpha[r] = __expf(m_r[r] - mn);
            m_r[r] = mn;
        }
        float rowsum[4];
        #pragma unroll
        for (int r = 0; r < 4; r++) rowsum[r] = 0.f;
        #pragma unroll
        for (int kn = 0; kn < 4; kn++)
            #pragma unroll
            for (int r = 0; r < 4; r++) {
                float p = __expf(sv[kn][r] - m_r[r]);
                sv[kn][r] = p;
                rowsum[r] += p;
            }
        #pragma unroll
        for (int r = 0; r < 4; r++) {
            float rs = rowsum[r];
            #pragma unroll
            for (int off = 1; off < 16; off <<= 1) rs += __shfl_xor(rs, off);
            l_r[r] = l_r[r]*alpha[r] + rs;
        }
        #pragma unroll
        for (int dn = 0; dn < 4; dn++)
            #pragma unroll
            for (int r = 0; r < 4; r++) o[dn][r] *= alpha[r];

        // ---- P -> bf16 via wave-private LDS round trip (C-layout -> A-layout)
        short* ps = Ps[w];
        #pragma unroll
        for (int kn = 0; kn < 4; kn++)
            #pragma unroll
            for (int r = 0; r < 4; r++)
                ps[(quad*4 + r)*PS_LD + kn*16 + lc] = f2bf(sv[kn][r]);
        __asm__ volatile("s_waitcnt lgkmcnt(0)" ::: "memory");
        bf16x8 pf0 = *(const bf16x8*)(ps + lc*PS_LD + quad*8);
        bf16x8 pf1 = *(const bf16x8*)(ps + lc*PS_LD + 32 + quad*8);

        // ---- O += P V : 4 d-blocks of 16, each 2 MFMAs over key=64
        #pragma unroll
        for (int dn = 0; dn < 4; dn++) {
            const short* vr = Vt + (dn*16 + lc)*64;
            bf16x8 vf0 = *(const bf16x8*)(vr + quad*8);
            bf16x8 vf1 = *(const bf16x8*)(vr + 32 + quad*8);
            o[dn] = __builtin_amdgcn_mfma_f32_16x16x32_bf16(pf0, vf0, o[dn], 0, 0, 0);
            o[dn] = __builtin_amdgcn_mfma_f32_16x16x32_bf16(pf1, vf1, o[dn], 0, 0, 0);
        }
    }

    // ---- epilogue: y[row][h*64+d] = o/l * gate
    #pragma unroll
    for (int r = 0; r < 4; r++) {
        int row = b*2048 + qt*64 + w*16 + quad*4 + r;
        float g = gate[(size_t)row*16 + h] / l_r[r];
        #pragma unroll
        for (int dn = 0; dn < 4; dn++)
            y[(size_t)row*1024 + h*64 + dn*16 + lc] = o[dn][r] * g;
    }
}

extern "C" void kernel_launch(void* const* d_in, const int* in_sizes, int n_in,
                              void* d_out, int out_size, void* d_ws, size_t ws_size,
                              hipStream_t stream) {
    (void)in_sizes; (void)n_in; (void)out_size; (void)ws_size;
    const float* x  = (const float*)d_in[0];
    const float* qw = (const float*)d_in[1];
    const float* kw = (const float*)d_in[2];
    const float* vw = (const float*)d_in[3];
    const float* ow = (const float*)d_in[4];
    const float* ve = (const float*)d_in[5];
    const float* v0 = (const float*)d_in[6];
    const float* qg = (const float*)d_in[7];
    const float* vl = (const float*)d_in[8];
    const float* gw = (const float*)d_in[9];
    const float* gb = (const float*)d_in[10];

    float* out  = (float*)d_out;
    float* rawv = out + (size_t)BB*TT*DD;

    float* ws  = (float*)d_ws;
    float* qkv = ws;                                // 4096*1536 f32, reused as y after epilogue
    short* qbh = (short*)(ws + 6291456);            // 2*16*2048*64 bf16
    short* kbh = qbh + 4194304;                     // 2*4*2048*64 bf16
    short* vtb = kbh + 1048576;                     // 2*4*64*2048 bf16 (transposed)
    float* gt  = (float*)(vtb + 1048576);           // 4096*16 f32
    float* y   = qkv;

    gemm_qkv<<<dim3(24, 64), 256, 0, stream>>>(x, qw, kw, vw, ve, qkv);
    qkv_epilogue<<<24576, 256, 0, stream>>>(qkv, v0, qg, vl, qbh, kbh, vtb, rawv);
    gate_kernel<<<4096, 256, 0, stream>>>(x, gw, gb, gt);
    flash_mfma<<<dim3(32, 32), 256, 0, stream>>>(qbh, kbh, vtb, gt, y);
    gemm_out<<<dim3(16, 64), 256, 0, stream>>>(y, ow, out);
}

// Round 3
// 303.878 us; speedup vs baseline: 6.5729x; 2.3485x over previous
//
#include <hip/hip_runtime.h>
#include <math.h>

#define BB 2
#define TT 2048
#define DD 1024
#define NH 16
#define NKV 4
#define HD 64
#define EPSF 1.1920929e-07f
// T=2048 > TSL=1024 -> nb = 10000 * 2^(64/62); log2(nb) = log2(1e4) + 64/62
#define LOG2_NB 14.319970444065578

typedef __attribute__((ext_vector_type(8))) short bf16x8;
typedef __attribute__((ext_vector_type(4))) float f32x4;

__device__ inline short f2bf(float f) {
    unsigned u = __builtin_bit_cast(unsigned, f);
    unsigned r = (u + 0x7fffu + ((u >> 16) & 1u)) >> 16;
    return (short)r;
}

// ---------------- fp32 -> bf16 conversion (vectorized) ----------------
__global__ __launch_bounds__(256) void conv_bf16(
    const float* __restrict__ s, short* __restrict__ d, int n4)
{
    int i = blockIdx.x * 256 + threadIdx.x;
    if (i < n4) {
        float4 v = ((const float4*)s)[i];
        short4 o;
        o.x = f2bf(v.x); o.y = f2bf(v.y); o.z = f2bf(v.z); o.w = f2bf(v.w);
        ((short4*)d)[i] = o;
    }
}

// ---------------- bf16 MFMA GEMM (m97 structure): C[m][n] = dot(A[m,:], B[n,:]) ----------------
// 128x128 tile, BK=32, 256 threads = 4 waves (2x2 of 64x64), K=1024 fixed.
// Optional ve-add epilogue for n>=1280 (QKV's v block).
__global__ __launch_bounds__(256) void gemm_mfma(
    const short* __restrict__ A, const short* __restrict__ Bmat,
    const float* __restrict__ ve, float* __restrict__ C, int ldc)
{
    __shared__ short As[128*32];
    __shared__ short Bs[128*32];
    int tid = threadIdx.x;
    int w = tid >> 6, lane = tid & 63;
    int quad = lane >> 4, lc = lane & 15;
    int wy = w >> 1, wx = w & 1;
    int m0 = blockIdx.y * 128, n0 = blockIdx.x * 128;

    f32x4 acc[4][4];
    #pragma unroll
    for (int i = 0; i < 4; i++)
        #pragma unroll
        for (int j = 0; j < 4; j++) acc[i][j] = (f32x4){0.f,0.f,0.f,0.f};

    for (int k0 = 0; k0 < 1024; k0 += 32) {
        __syncthreads();
        #pragma unroll
        for (int i = 0; i < 2; i++) {
            int off = w*2048 + i*1024;        // byte offset into 8KB LDS tile (wave-uniform)
            int f = off + lane*16;
            int row = f >> 6, col = (f & 63) >> 1;   // 64B per row of 32 bf16
            const short* ga = A + (size_t)(m0 + row)*1024 + k0 + col;
            __builtin_amdgcn_global_load_lds(
                (const __attribute__((address_space(1))) void*)ga,
                (__attribute__((address_space(3))) void*)((char*)As + off), 16, 0, 0);
            const short* gb = Bmat + (size_t)(n0 + row)*1024 + k0 + col;
            __builtin_amdgcn_global_load_lds(
                (const __attribute__((address_space(1))) void*)gb,
                (__attribute__((address_space(3))) void*)((char*)Bs + off), 16, 0, 0);
        }
        __syncthreads();

        bf16x8 af[4], bfr[4];
        #pragma unroll
        for (int tm = 0; tm < 4; tm++)
            af[tm] = *(const bf16x8*)(As + (wy*64 + tm*16 + lc)*32 + quad*8);
        #pragma unroll
        for (int tn = 0; tn < 4; tn++)
            bfr[tn] = *(const bf16x8*)(Bs + (wx*64 + tn*16 + lc)*32 + quad*8);
        #pragma unroll
        for (int tm = 0; tm < 4; tm++)
            #pragma unroll
            for (int tn = 0; tn < 4; tn++)
                acc[tm][tn] = __builtin_amdgcn_mfma_f32_16x16x32_bf16(af[tm], bfr[tn], acc[tm][tn], 0, 0, 0);
    }

    #pragma unroll
    for (int tm = 0; tm < 4; tm++)
        #pragma unroll
        for (int r = 0; r < 4; r++) {
            int m = m0 + wy*64 + tm*16 + quad*4 + r;
            #pragma unroll
            for (int tn = 0; tn < 4; tn++) {
                int n = n0 + wx*64 + tn*16 + lc;
                float v = acc[tm][tn][r];
                if (ve && n >= 1280) v += ve[(size_t)m*256 + (n - 1280)];
                C[(size_t)m*ldc + n] = v;
            }
        }
}

// ---------------- epilogue: RMSNorm + RoPE + gain (q,k) -> bf16; v mix -> bf16 V^T; raw_v fp32 ----------------
__global__ __launch_bounds__(256) void qkv_epilogue(
    const float* __restrict__ qkv, const float* __restrict__ v0,
    const float* __restrict__ q_gain, const float* __restrict__ vr_lambda,
    short* __restrict__ qbh, short* __restrict__ kbh, short* __restrict__ vtb,
    float* __restrict__ rawv)
{
    int wave = blockIdx.x * 4 + (threadIdx.x >> 6);
    int lane = threadIdx.x & 63;
    int row = wave / 24;     // 0..4095  (b*T + t)
    int hh  = wave % 24;
    int b = row >> 11;
    int t = row & (TT - 1);

    if (hh < 20) {
        int col = (hh < 16) ? (hh*64 + lane) : (1024 + (hh-16)*64 + lane);
        float val = qkv[(size_t)row*1536 + col];
        float ss = val * val;
        #pragma unroll
        for (int off = 32; off; off >>= 1) ss += __shfl_xor(ss, off);
        val *= rsqrtf(ss * (1.0f/64.0f) + EPSF);
        float partner = __shfl(val, lane ^ 32);
        int idx = lane & 31;
        float inv = (float)exp2((double)idx * (-LOG2_NB / 32.0));
        float fr = (float)t * inv;
        float sn, cs;
        sincosf(fr, &sn, &cs);
        float outv = (lane < 32) ? (val*cs + partner*sn) : (val*cs - partner*sn);
        if (hh < 16) {
            outv *= q_gain[hh];
            qbh[(((size_t)(b*16 + hh))*2048 + t)*64 + lane] = f2bf(outv);
        } else {
            kbh[(((size_t)(b*4 + (hh-16)))*2048 + t)*64 + lane] = f2bf(outv);
        }
    } else {
        int vh = hh - 20;
        size_t off = ((size_t)row*4 + vh)*64 + lane;
        float vraw = qkv[(size_t)row*1536 + 1280 + vh*64 + lane];
        rawv[off] = vraw;
        float vmix = vr_lambda[0]*v0[off] + vr_lambda[1]*vraw;
        // V^T: [b][kvh][d=lane][t]
        vtb[(((size_t)(b*4 + vh))*64 + lane)*2048 + t] = f2bf(vmix);
    }
}

// ---------------- gate: sigmoid(x @ gate_w.T + gate_b) ----------------
__global__ __launch_bounds__(256) void gate_kernel(
    const float* __restrict__ x, const float* __restrict__ gw,
    const float* __restrict__ gb, float* __restrict__ gate)
{
    __shared__ float xs[1024];
    int row = blockIdx.x;
    int tid = threadIdx.x;
    *(float4*)&xs[tid*4] = *(const float4*)&x[(size_t)row*1024 + tid*4];
    __syncthreads();
    int wave = tid >> 6, lane = tid & 63;
    for (int h = wave; h < 16; h += 4) {
        const float* w = gw + (size_t)h * 1024;
        float s = 0.f;
        #pragma unroll
        for (int i = 0; i < 16; i++) s += xs[lane + 64*i] * w[lane + 64*i];
        #pragma unroll
        for (int off = 32; off; off >>= 1) s += __shfl_xor(s, off);
        if (lane == 0) gate[(size_t)row*16 + h] = 1.0f / (1.0f + __expf(-(s + gb[h])));
    }
}

// ---------------- MFMA flash attention (bf16 inputs, fp32 accumulate) ----------------
#define PS_LD 72   // Ps row stride in shorts (144B: 16B-aligned frag reads)
__global__ __launch_bounds__(256) void flash_mfma(
    const short* __restrict__ qbh, const short* __restrict__ kbh,
    const short* __restrict__ vtb, const float* __restrict__ gate,
    short* __restrict__ y16)
{
    __shared__ short Ks[64*64];
    __shared__ short Vt[64*64];
    __shared__ short Ps[4][16*PS_LD];

    int bh = blockIdx.x;             // b*16 + h
    int b = bh >> 4, h = bh & 15, kvh = h >> 2;
    int qt = blockIdx.y;
    int tid = threadIdx.x;
    int w = tid >> 6, lane = tid & 63;
    int quad = lane >> 4, lc = lane & 15;

    const short* qbase = qbh + (((size_t)bh)*2048 + qt*64 + w*16 + lc)*64;
    bf16x8 qf0 = *(const bf16x8*)(qbase + quad*8);
    bf16x8 qf1 = *(const bf16x8*)(qbase + 32 + quad*8);

    f32x4 o[4];
    #pragma unroll
    for (int i = 0; i < 4; i++) o[i] = (f32x4){0.f,0.f,0.f,0.f};
    float m_r[4], l_r[4];
    #pragma unroll
    for (int r = 0; r < 4; r++) { m_r[r] = -1e30f; l_r[r] = 0.f; }
    const float scale = 0.125f;

    const size_t ktile_base = (((size_t)(b*4 + kvh))*2048) * 64;   // K [t][d]
    const size_t vrow_base  = (((size_t)(b*4 + kvh))*64) * 2048;   // V^T [d][t]

    for (int kt = 0; kt <= qt; kt++) {
        __syncthreads();
        #pragma unroll
        for (int i = 0; i < 2; i++) {
            int off = w*2048 + i*1024;
            const short* gp = kbh + ktile_base + (size_t)(kt*64)*64 + (off + lane*16)/2;
            __builtin_amdgcn_global_load_lds(
                (const __attribute__((address_space(1))) void*)gp,
                (__attribute__((address_space(3))) void*)((char*)Ks + off), 16, 0, 0);
        }
        #pragma unroll
        for (int i = 0; i < 2; i++) {
            int off = w*2048 + i*1024;
            int f = off + lane*16;
            int d = f >> 7, cb = f & 127;
            const short* gp = vtb + vrow_base + (size_t)d*2048 + kt*64 + cb/2;
            __builtin_amdgcn_global_load_lds(
                (const __attribute__((address_space(1))) void*)gp,
                (__attribute__((address_space(3))) void*)((char*)Vt + off), 16, 0, 0);
        }
        __syncthreads();

        f32x4 s4[4];
        #pragma unroll
        for (int kn = 0; kn < 4; kn++) {
            const short* kr = Ks + (kn*16 + lc)*64;
            bf16x8 kf0 = *(const bf16x8*)(kr + quad*8);
            bf16x8 kf1 = *(const bf16x8*)(kr + 32 + quad*8);
            f32x4 acc = (f32x4){0.f,0.f,0.f,0.f};
            acc = __builtin_amdgcn_mfma_f32_16x16x32_bf16(qf0, kf0, acc, 0, 0, 0);
            acc = __builtin_amdgcn_mfma_f32_16x16x32_bf16(qf1, kf1, acc, 0, 0, 0);
            s4[kn] = acc;
        }

        bool diag = (kt == qt);
        float sv[4][4];
        #pragma unroll
        for (int kn = 0; kn < 4; kn++)
            #pragma unroll
            for (int r = 0; r < 4; r++) {
                float s = s4[kn][r] * scale;
                if (diag && (kn*16 + lc > w*16 + quad*4 + r)) s = -1e30f;
                sv[kn][r] = s;
            }
        float alpha[4];
        #pragma unroll
        for (int r = 0; r < 4; r++) {
            float mn = fmaxf(fmaxf(sv[0][r], sv[1][r]), fmaxf(sv[2][r], sv[3][r]));
            #pragma unroll
            for (int off = 1; off < 16; off <<= 1) mn = fmaxf(mn, __shfl_xor(mn, off));
            mn = fmaxf(mn, m_r[r]);
            alpha[r] = __expf(m_r[r] - mn);
            m_r[r] = mn;
        }
        float rowsum[4];
        #pragma unroll
        for (int r = 0; r < 4; r++) rowsum[r] = 0.f;
        #pragma unroll
        for (int kn = 0; kn < 4; kn++)
            #pragma unroll
            for (int r = 0; r < 4; r++) {
                float p = __expf(sv[kn][r] - m_r[r]);
                sv[kn][r] = p;
                rowsum[r] += p;
            }
        #pragma unroll
        for (int r = 0; r < 4; r++) {
            float rs = rowsum[r];
            #pragma unroll
            for (int off = 1; off < 16; off <<= 1) rs += __shfl_xor(rs, off);
            l_r[r] = l_r[r]*alpha[r] + rs;
        }
        #pragma unroll
        for (int dn = 0; dn < 4; dn++)
            #pragma unroll
            for (int r = 0; r < 4; r++) o[dn][r] *= alpha[r];

        short* ps = Ps[w];
        #pragma unroll
        for (int kn = 0; kn < 4; kn++)
            #pragma unroll
            for (int r = 0; r < 4; r++)
                ps[(quad*4 + r)*PS_LD + kn*16 + lc] = f2bf(sv[kn][r]);
        __asm__ volatile("s_waitcnt lgkmcnt(0)" ::: "memory");
        bf16x8 pf0 = *(const bf16x8*)(ps + lc*PS_LD + quad*8);
        bf16x8 pf1 = *(const bf16x8*)(ps + lc*PS_LD + 32 + quad*8);

        #pragma unroll
        for (int dn = 0; dn < 4; dn++) {
            const short* vr = Vt + (dn*16 + lc)*64;
            bf16x8 vf0 = *(const bf16x8*)(vr + quad*8);
            bf16x8 vf1 = *(const bf16x8*)(vr + 32 + quad*8);
            o[dn] = __builtin_amdgcn_mfma_f32_16x16x32_bf16(pf0, vf0, o[dn], 0, 0, 0);
            o[dn] = __builtin_amdgcn_mfma_f32_16x16x32_bf16(pf1, vf1, o[dn], 0, 0, 0);
        }
    }

    #pragma unroll
    for (int r = 0; r < 4; r++) {
        int row = b*2048 + qt*64 + w*16 + quad*4 + r;
        float g = gate[(size_t)row*16 + h] / l_r[r];
        #pragma unroll
        for (int dn = 0; dn < 4; dn++)
            y16[(size_t)row*1024 + h*64 + dn*16 + lc] = f2bf(o[dn][r] * g);
    }
}

extern "C" void kernel_launch(void* const* d_in, const int* in_sizes, int n_in,
                              void* d_out, int out_size, void* d_ws, size_t ws_size,
                              hipStream_t stream) {
    (void)in_sizes; (void)n_in; (void)out_size; (void)ws_size;
    const float* x  = (const float*)d_in[0];
    const float* qw = (const float*)d_in[1];
    const float* kw = (const float*)d_in[2];
    const float* vw = (const float*)d_in[3];
    const float* ow = (const float*)d_in[4];
    const float* ve = (const float*)d_in[5];
    const float* v0 = (const float*)d_in[6];
    const float* qg = (const float*)d_in[7];
    const float* vl = (const float*)d_in[8];
    const float* gw = (const float*)d_in[9];
    const float* gb = (const float*)d_in[10];

    float* out  = (float*)d_out;
    float* rawv = out + (size_t)BB*TT*DD;

    // workspace layout (floats)
    float* ws   = (float*)d_ws;
    float* qkv  = ws;                               // 4096*1536 f32 (25MB); y16 reuses this region later
    float* p    = ws + 6291456;
    short* x16  = (short*)p;        p += 2097152;   // 4096*1024 bf16
    short* wb16 = (short*)p;        p += 786432;    // 1536*1024 bf16 (qw|kw|vw)
    short* ow16 = (short*)p;        p += 524288;    // 1024*1024 bf16
    short* qbh  = (short*)p;        p += 2097152;   // 2*16*2048*64 bf16
    short* kbh  = (short*)p;        p += 524288;    // 2*4*2048*64 bf16
    short* vtb  = (short*)p;        p += 524288;    // 2*4*64*2048 bf16 (transposed)
    float* gt   = p;                                // 4096*16 f32
    short* y16  = (short*)qkv;                      // 4096*1024 bf16, reuses qkv region

    // conversions
    conv_bf16<<<4096, 256, 0, stream>>>(x,  x16, 1048576);
    conv_bf16<<<1024, 256, 0, stream>>>(qw, wb16, 262144);
    conv_bf16<<<256,  256, 0, stream>>>(kw, wb16 + 1048576, 65536);
    conv_bf16<<<256,  256, 0, stream>>>(vw, wb16 + 1310720, 65536);
    conv_bf16<<<1024, 256, 0, stream>>>(ow, ow16, 262144);

    // QKV projection: M=4096, N=1536
    gemm_mfma<<<dim3(12, 32), 256, 0, stream>>>(x16, wb16, ve, qkv, 1536);
    qkv_epilogue<<<24576, 256, 0, stream>>>(qkv, v0, qg, vl, qbh, kbh, vtb, rawv);
    gate_kernel<<<4096, 256, 0, stream>>>(x, gw, gb, gt);
    flash_mfma<<<dim3(32, 32), 256, 0, stream>>>(qbh, kbh, vtb, gt, y16);
    // out projection: M=4096, N=1024
    gemm_mfma<<<dim3(8, 32), 256, 0, stream>>>(y16, ow16, nullptr, out, 1024);
}

// Round 4
// 271.589 us; speedup vs baseline: 7.3543x; 1.1189x over previous
//
#include <hip/hip_runtime.h>
#include <math.h>

#define BB 2
#define TT 2048
#define DD 1024
#define NH 16
#define NKV 4
#define HD 64
#define EPSF 1.1920929e-07f
// T=2048 > TSL=1024 -> nb = 10000 * 2^(64/62); log2(nb) = log2(1e4) + 64/62
#define LOG2_NB 14.319970444065578
// 0.125 (1/sqrt(64)) * log2(e): folded into q so softmax runs in exp2 domain
#define SCALE_LOG2E 0.18033688011112042f

typedef __attribute__((ext_vector_type(8))) short bf16x8;
typedef __attribute__((ext_vector_type(4))) float f32x4;

__device__ inline short f2bf(float f) {
    unsigned u = __builtin_bit_cast(unsigned, f);
    unsigned r = (u + 0x7fffu + ((u >> 16) & 1u)) >> 16;
    return (short)r;
}

// ---------------- fused fp32 -> bf16 conversion for all 5 tensors ----------------
__global__ __launch_bounds__(256) void conv_all(
    const float* __restrict__ x, const float* __restrict__ qw,
    const float* __restrict__ kw, const float* __restrict__ vw,
    const float* __restrict__ ow,
    short* __restrict__ x16, short* __restrict__ wb16, short* __restrict__ ow16)
{
    int i = blockIdx.x * 256 + threadIdx.x;   // float4 index, total 1703936
    const float* src; short* dst; int j;
    if (i < 1048576)      { src = x;  dst = x16;            j = i; }
    else if (i < 1310720) { src = qw; dst = wb16;           j = i - 1048576; }
    else if (i < 1376256) { src = kw; dst = wb16 + 1048576; j = i - 1310720; }
    else if (i < 1441792) { src = vw; dst = wb16 + 1310720; j = i - 1376256; }
    else                  { src = ow; dst = ow16;           j = i - 1441792; }
    float4 v = ((const float4*)src)[j];
    short4 o;
    o.x = f2bf(v.x); o.y = f2bf(v.y); o.z = f2bf(v.z); o.w = f2bf(v.w);
    ((short4*)dst)[j] = o;
}

// ---------------- bf16 MFMA GEMM (m97 structure, swizzled LDS): C = A * B^T ----------------
// 128x128 tile, BK=32, 256 threads = 4 waves (2x2 of 64x64), K=1024 fixed.
__global__ __launch_bounds__(256) void gemm_mfma(
    const short* __restrict__ A, const short* __restrict__ Bmat,
    const float* __restrict__ ve, float* __restrict__ C, int ldc)
{
    __shared__ short As[128*32];
    __shared__ short Bs[128*32];
    int tid = threadIdx.x;
    int w = tid >> 6, lane = tid & 63;
    int quad = lane >> 4, lc = lane & 15;
    int wy = w >> 1, wx = w & 1;
    int m0 = blockIdx.y * 128, n0 = blockIdx.x * 128;

    f32x4 acc[4][4];
    #pragma unroll
    for (int i = 0; i < 4; i++)
        #pragma unroll
        for (int j = 0; j < 4; j++) acc[i][j] = (f32x4){0.f,0.f,0.f,0.f};

    for (int k0 = 0; k0 < 1024; k0 += 32) {
        __syncthreads();
        #pragma unroll
        for (int i = 0; i < 2; i++) {
            int off = w*2048 + i*1024;            // byte offset (wave-uniform)
            int g = (off >> 4) + lane;            // 16B chunk idx
            int row = g >> 2, c = g & 3;
            int cg = c ^ (row & 3);               // XOR swizzle
            const short* ga = A + (size_t)(m0 + row)*1024 + k0 + cg*8;
            __builtin_amdgcn_global_load_lds(
                (const __attribute__((address_space(1))) void*)ga,
                (__attribute__((address_space(3))) void*)((char*)As + off), 16, 0, 0);
            const short* gb = Bmat + (size_t)(n0 + row)*1024 + k0 + cg*8;
            __builtin_amdgcn_global_load_lds(
                (const __attribute__((address_space(1))) void*)gb,
                (__attribute__((address_space(3))) void*)((char*)Bs + off), 16, 0, 0);
        }
        __syncthreads();

        bf16x8 af[4], bfr[4];
        #pragma unroll
        for (int tm = 0; tm < 4; tm++) {
            int row = wy*64 + tm*16 + lc;
            af[tm] = *(const bf16x8*)(As + row*32 + ((quad*8) ^ ((row&3)*8)));
        }
        #pragma unroll
        for (int tn = 0; tn < 4; tn++) {
            int row = wx*64 + tn*16 + lc;
            bfr[tn] = *(const bf16x8*)(Bs + row*32 + ((quad*8) ^ ((row&3)*8)));
        }
        #pragma unroll
        for (int tm = 0; tm < 4; tm++)
            #pragma unroll
            for (int tn = 0; tn < 4; tn++)
                acc[tm][tn] = __builtin_amdgcn_mfma_f32_16x16x32_bf16(af[tm], bfr[tn], acc[tm][tn], 0, 0, 0);
    }

    #pragma unroll
    for (int tm = 0; tm < 4; tm++)
        #pragma unroll
        for (int r = 0; r < 4; r++) {
            int m = m0 + wy*64 + tm*16 + quad*4 + r;
            #pragma unroll
            for (int tn = 0; tn < 4; tn++) {
                int n = n0 + wx*64 + tn*16 + lc;
                float v = acc[tm][tn][r];
                if (ve && n >= 1280) v += ve[(size_t)m*256 + (n - 1280)];
                C[(size_t)m*ldc + n] = v;
            }
        }
}

// ---------------- epilogue: RMSNorm + RoPE + gain*scale (q,k) -> bf16; v mix -> bf16 (coalesced) ----------------
__global__ __launch_bounds__(256) void qkv_epilogue(
    const float* __restrict__ qkv, const float* __restrict__ v0,
    const float* __restrict__ q_gain, const float* __restrict__ vr_lambda,
    short* __restrict__ qbh, short* __restrict__ kbh, short* __restrict__ vb,
    float* __restrict__ rawv)
{
    int wave = blockIdx.x * 4 + (threadIdx.x >> 6);
    int lane = threadIdx.x & 63;
    int row = wave / 24;     // 0..4095  (b*T + t)
    int hh  = wave % 24;
    int b = row >> 11;
    int t = row & (TT - 1);

    if (hh < 20) {
        int col = (hh < 16) ? (hh*64 + lane) : (1024 + (hh-16)*64 + lane);
        float val = qkv[(size_t)row*1536 + col];
        float ss = val * val;
        #pragma unroll
        for (int off = 32; off; off >>= 1) ss += __shfl_xor(ss, off);
        val *= rsqrtf(ss * (1.0f/64.0f) + EPSF);
        float partner = __shfl(val, lane ^ 32);
        int idx = lane & 31;
        float inv = (float)exp2((double)idx * (-LOG2_NB / 32.0));
        float fr = (float)t * inv;
        float sn, cs;
        sincosf(fr, &sn, &cs);
        float outv = (lane < 32) ? (val*cs + partner*sn) : (val*cs - partner*sn);
        if (hh < 16) {
            outv *= q_gain[hh] * SCALE_LOG2E;    // fold softmax scale+log2e into q
            qbh[(((size_t)(b*16 + hh))*2048 + t)*64 + lane] = f2bf(outv);
        } else {
            kbh[(((size_t)(b*4 + (hh-16)))*2048 + t)*64 + lane] = f2bf(outv);
        }
    } else {
        int vh = hh - 20;
        size_t off = ((size_t)row*4 + vh)*64 + lane;
        float vraw = qkv[(size_t)row*1536 + 1280 + vh*64 + lane];
        rawv[off] = vraw;
        float vmix = vr_lambda[0]*v0[off] + vr_lambda[1]*vraw;
        vb[off] = f2bf(vmix);                    // coalesced [b][t][kvh][d]
    }
}

// ---------------- V transpose: vb [b][t][kvh][d] -> vtb [b*4+kvh][d][t] ----------------
__global__ __launch_bounds__(256) void transpose_v(
    const short* __restrict__ vb, short* __restrict__ vtb)
{
    __shared__ short tile[64][72];
    int bk = blockIdx.x;           // b*4+kvh
    int tt = blockIdx.y;           // t tile (64)
    int b = bk >> 2, kvh = bk & 3;
    int tid = threadIdx.x;
    int t4 = tid >> 4;             // 0..15
    int d4 = (tid & 15) * 4;       // 0..60
    #pragma unroll
    for (int i = 0; i < 4; i++) {
        int t = t4 + i*16;
        const short* src = vb + (((size_t)(b*2048 + tt*64 + t)*4 + kvh)*64 + d4);
        *(short4*)&tile[t][d4] = *(const short4*)src;
    }
    __syncthreads();
    #pragma unroll
    for (int i = 0; i < 4; i++) {
        int d = t4 + i*16;
        int t0 = d4;
        short4 o;
        o.x = tile[t0+0][d]; o.y = tile[t0+1][d];
        o.z = tile[t0+2][d]; o.w = tile[t0+3][d];
        *(short4*)&vtb[((size_t)(bk*64 + d))*2048 + tt*64 + t0] = o;
    }
}

// ---------------- gate: sigmoid(x @ gate_w.T + gate_b) ----------------
__global__ __launch_bounds__(256) void gate_kernel(
    const float* __restrict__ x, const float* __restrict__ gw,
    const float* __restrict__ gb, float* __restrict__ gate)
{
    __shared__ float xs[1024];
    int row = blockIdx.x;
    int tid = threadIdx.x;
    *(float4*)&xs[tid*4] = *(const float4*)&x[(size_t)row*1024 + tid*4];
    __syncthreads();
    int wave = tid >> 6, lane = tid & 63;
    for (int h = wave; h < 16; h += 4) {
        const float* w = gw + (size_t)h * 1024;
        float s = 0.f;
        #pragma unroll
        for (int i = 0; i < 16; i++) s += xs[lane + 64*i] * w[lane + 64*i];
        #pragma unroll
        for (int off = 32; off; off >>= 1) s += __shfl_xor(s, off);
        if (lane == 0) gate[(size_t)row*16 + h] = 1.0f / (1.0f + __expf(-(s + gb[h])));
    }
}

// ---------------- MFMA flash attention: paired q-tiles, double-buffered, swizzled LDS ----------------
#define PS_LD 72
__device__ inline void flash_step(
    const short* __restrict__ KsBuf, const short* __restrict__ VtBuf, short* __restrict__ ps,
    bf16x8 qf0, bf16x8 qf1,
    f32x4 (&o)[4], float (&m_r)[4], float (&l_r)[4],
    int quad, int lc, int rowbase, bool diag)
{
    // S = Q K^T (exp2-domain scores: scale folded into Q)
    f32x4 s4[4];
    #pragma unroll
    for (int kn = 0; kn < 4; kn++) {
        int row = kn*16 + lc;
        const short* kr = KsBuf + row*64;
        int sw = (row & 7) * 8;
        bf16x8 kf0 = *(const bf16x8*)(kr + ((quad*8) ^ sw));
        bf16x8 kf1 = *(const bf16x8*)(kr + ((quad*8 + 32) ^ sw));
        f32x4 acc = (f32x4){0.f,0.f,0.f,0.f};
        acc = __builtin_amdgcn_mfma_f32_16x16x32_bf16(qf0, kf0, acc, 0, 0, 0);
        acc = __builtin_amdgcn_mfma_f32_16x16x32_bf16(qf1, kf1, acc, 0, 0, 0);
        s4[kn] = acc;
    }
    float sv[4][4];
    #pragma unroll
    for (int kn = 0; kn < 4; kn++)
        #pragma unroll
        for (int r = 0; r < 4; r++) {
            float s = s4[kn][r];
            if (diag && (kn*16 + lc > rowbase + quad*4 + r)) s = -1e30f;
            sv[kn][r] = s;
        }
    float alpha[4];
    #pragma unroll
    for (int r = 0; r < 4; r++) {
        float mn = fmaxf(fmaxf(sv[0][r], sv[1][r]), fmaxf(sv[2][r], sv[3][r]));
        #pragma unroll
        for (int off = 1; off < 16; off <<= 1) mn = fmaxf(mn, __shfl_xor(mn, off));
        mn = fmaxf(mn, m_r[r]);
        alpha[r] = exp2f(m_r[r] - mn);
        m_r[r] = mn;
    }
    float rowsum[4] = {0.f, 0.f, 0.f, 0.f};
    #pragma unroll
    for (int kn = 0; kn < 4; kn++)
        #pragma unroll
        for (int r = 0; r < 4; r++) {
            float p = exp2f(sv[kn][r] - m_r[r]);
            sv[kn][r] = p;
            rowsum[r] += p;
        }
    #pragma unroll
    for (int r = 0; r < 4; r++) {
        float rs = rowsum[r];
        #pragma unroll
        for (int off = 1; off < 16; off <<= 1) rs += __shfl_xor(rs, off);
        l_r[r] = l_r[r]*alpha[r] + rs;
    }
    #pragma unroll
    for (int dn = 0; dn < 4; dn++)
        #pragma unroll
        for (int r = 0; r < 4; r++) o[dn][r] *= alpha[r];

    // P: C-layout -> bf16 A-layout via wave-private LDS
    #pragma unroll
    for (int kn = 0; kn < 4; kn++)
        #pragma unroll
        for (int r = 0; r < 4; r++)
            ps[(quad*4 + r)*PS_LD + kn*16 + lc] = f2bf(sv[kn][r]);
    __asm__ volatile("s_waitcnt lgkmcnt(0)" ::: "memory");
    bf16x8 pf0 = *(const bf16x8*)(ps + lc*PS_LD + quad*8);
    bf16x8 pf1 = *(const bf16x8*)(ps + lc*PS_LD + 32 + quad*8);

    #pragma unroll
    for (int dn = 0; dn < 4; dn++) {
        int row = dn*16 + lc;
        const short* vr = VtBuf + row*64;
        int sw = (row & 7) * 8;
        bf16x8 vf0 = *(const bf16x8*)(vr + ((quad*8) ^ sw));
        bf16x8 vf1 = *(const bf16x8*)(vr + ((quad*8 + 32) ^ sw));
        o[dn] = __builtin_amdgcn_mfma_f32_16x16x32_bf16(pf0, vf0, o[dn], 0, 0, 0);
        o[dn] = __builtin_amdgcn_mfma_f32_16x16x32_bf16(pf1, vf1, o[dn], 0, 0, 0);
    }
}

__global__ __launch_bounds__(256, 2) void flash_mfma(
    const short* __restrict__ qbh, const short* __restrict__ kbh,
    const short* __restrict__ vtb, const float* __restrict__ gate,
    short* __restrict__ y16)
{
    __shared__ short Ks[2][64*64];
    __shared__ short Vt[2][64*64];
    __shared__ short Ps[4][16*PS_LD];

    int bh = blockIdx.x;             // b*16 + h
    int b = bh >> 4, h = bh & 15, kvh = h >> 2;
    int j = blockIdx.y;              // 0..15 -> paired tiles (j, 31-j)
    int qtA = j, qtB = 31 - j;
    int tid = threadIdx.x;
    int w = tid >> 6, lane = tid & 63;
    int quad = lane >> 4, lc = lane & 15;

    const short* qbaseA = qbh + (((size_t)bh)*2048 + qtA*64 + w*16 + lc)*64;
    bf16x8 qA0 = *(const bf16x8*)(qbaseA + quad*8);
    bf16x8 qA1 = *(const bf16x8*)(qbaseA + 32 + quad*8);
    const short* qbaseB = qbh + (((size_t)bh)*2048 + qtB*64 + w*16 + lc)*64;
    bf16x8 qB0 = *(const bf16x8*)(qbaseB + quad*8);
    bf16x8 qB1 = *(const bf16x8*)(qbaseB + 32 + quad*8);

    f32x4 oA[4], oB[4];
    float mA[4], lA[4], mB[4], lB[4];
    #pragma unroll
    for (int i = 0; i < 4; i++) {
        oA[i] = (f32x4){0.f,0.f,0.f,0.f};
        oB[i] = (f32x4){0.f,0.f,0.f,0.f};
        mA[i] = -1e30f; lA[i] = 0.f; mB[i] = -1e30f; lB[i] = 0.f;
    }

    const size_t kbase = ((size_t)(b*4 + kvh))*2048*64;   // K [t][d]
    const size_t vbase = ((size_t)(b*4 + kvh))*64*2048;   // V^T [d][t]

    // ---- staging helper (XOR-swizzled via global address permutation) ----
    #define STAGE(buf, kt)                                                              \
    {                                                                                   \
        _Pragma("unroll")                                                               \
        for (int i = 0; i < 2; i++) {                                                   \
            int off = w*2048 + i*1024;                                                  \
            int g = (off >> 4) + lane;                                                  \
            int row = g >> 3, c = g & 7;                                                \
            int cg = c ^ (row & 7);                                                     \
            const short* gk = kbh + kbase + (size_t)((kt)*64 + row)*64 + cg*8;          \
            __builtin_amdgcn_global_load_lds(                                           \
                (const __attribute__((address_space(1))) void*)gk,                      \
                (__attribute__((address_space(3))) void*)((char*)Ks[buf] + off), 16, 0, 0); \
            const short* gv = vtb + vbase + (size_t)row*2048 + (kt)*64 + cg*8;          \
            __builtin_amdgcn_global_load_lds(                                           \
                (const __attribute__((address_space(1))) void*)gv,                      \
                (__attribute__((address_space(3))) void*)((char*)Vt[buf] + off), 16, 0, 0); \
        }                                                                               \
    }

    STAGE(0, 0);
    __syncthreads();

    for (int kt = 0; kt <= qtB; kt++) {
        int cur = kt & 1;
        if (kt < qtB) STAGE(cur ^ 1, kt + 1);
        flash_step(Ks[cur], Vt[cur], Ps[w], qB0, qB1, oB, mB, lB, quad, lc, w*16, kt == qtB);
        if (kt <= qtA)
            flash_step(Ks[cur], Vt[cur], Ps[w], qA0, qA1, oA, mA, lA, quad, lc, w*16, kt == qtA);
        __syncthreads();
    }

    #pragma unroll
    for (int r = 0; r < 4; r++) {
        int rowA = b*2048 + qtA*64 + w*16 + quad*4 + r;
        float gA = gate[(size_t)rowA*16 + h] / lA[r];
        int rowB = b*2048 + qtB*64 + w*16 + quad*4 + r;
        float gB = gate[(size_t)rowB*16 + h] / lB[r];
        #pragma unroll
        for (int dn = 0; dn < 4; dn++) {
            y16[(size_t)rowA*1024 + h*64 + dn*16 + lc] = f2bf(oA[dn][r] * gA);
            y16[(size_t)rowB*1024 + h*64 + dn*16 + lc] = f2bf(oB[dn][r] * gB);
        }
    }
}

extern "C" void kernel_launch(void* const* d_in, const int* in_sizes, int n_in,
                              void* d_out, int out_size, void* d_ws, size_t ws_size,
                              hipStream_t stream) {
    (void)in_sizes; (void)n_in; (void)out_size; (void)ws_size;
    const float* x  = (const float*)d_in[0];
    const float* qw = (const float*)d_in[1];
    const float* kw = (const float*)d_in[2];
    const float* vw = (const float*)d_in[3];
    const float* ow = (const float*)d_in[4];
    const float* ve = (const float*)d_in[5];
    const float* v0 = (const float*)d_in[6];
    const float* qg = (const float*)d_in[7];
    const float* vl = (const float*)d_in[8];
    const float* gw = (const float*)d_in[9];
    const float* gb = (const float*)d_in[10];

    float* out  = (float*)d_out;
    float* rawv = out + (size_t)BB*TT*DD;

    // workspace layout (float units)
    float* ws   = (float*)d_ws;
    float* qkv  = ws;                               // 4096*1536 f32; y16 reuses later
    float* p    = ws + 6291456;
    short* x16  = (short*)p;        p += 2097152;   // 4096*1024 bf16
    short* wb16 = (short*)p;        p += 786432;    // 1536*1024 bf16 (qw|kw|vw)
    short* ow16 = (short*)p;        p += 524288;    // 1024*1024 bf16
    short* qbh  = (short*)p;        p += 2097152;   // [b*16+h][t][d] bf16
    short* kbh  = (short*)p;        p += 524288;    // [b*4+kvh][t][d] bf16
    short* vtb  = (short*)p;        p += 524288;    // [b*4+kvh][d][t] bf16
    short* vb   = (short*)p;        p += 524288;    // [b][t][kvh][d] bf16 (pre-transpose)
    float* gt   = p;                                // 4096*16 f32
    short* y16  = (short*)qkv;

    conv_all<<<6656, 256, 0, stream>>>(x, qw, kw, vw, ow, x16, wb16, ow16);
    // QKV projection: M=4096, N=1536
    gemm_mfma<<<dim3(12, 32), 256, 0, stream>>>(x16, wb16, ve, qkv, 1536);
    qkv_epilogue<<<24576, 256, 0, stream>>>(qkv, v0, qg, vl, qbh, kbh, vb, rawv);
    transpose_v<<<dim3(8, 32), 256, 0, stream>>>(vb, vtb);
    gate_kernel<<<4096, 256, 0, stream>>>(x, gw, gb, gt);
    flash_mfma<<<dim3(32, 16), 256, 0, stream>>>(qbh, kbh, vtb, gt, y16);
    // out projection: M=4096, N=1024
    gemm_mfma<<<dim3(8, 32), 256, 0, stream>>>(y16, ow16, nullptr, out, 1024);
}

// Round 5
// 242.179 us; speedup vs baseline: 8.2474x; 1.1214x over previous
//
#include <hip/hip_runtime.h>
#include <math.h>

#define BB 2
#define TT 2048
#define DD 1024
#define NH 16
#define NKV 4
#define HD 64
#define EPSF 1.1920929e-07f
// T=2048 > TSL=1024 -> nb = 10000 * 2^(64/62); log2(nb) = log2(1e4) + 64/62
#define LOG2_NB 14.319970444065578
// 0.125 (1/sqrt(64)) * log2(e): folded into q so softmax runs in exp2 domain
#define SCALE_LOG2E 0.18033688011112042f
// fixed softmax max (exp2 units): |q.k| <= 8*8*1.5*0.125*log2e = 17.31 < 17.5
#define FIXMAX 17.5f

typedef __attribute__((ext_vector_type(8))) short bf16x8;
typedef __attribute__((ext_vector_type(4))) float f32x4;

__device__ inline short f2bf(float f) {
    unsigned u = __builtin_bit_cast(unsigned, f);
    unsigned r = (u + 0x7fffu + ((u >> 16) & 1u)) >> 16;
    return (short)r;
}

// ---------------- fused fp32 -> bf16 conversion for all 5 tensors ----------------
__global__ __launch_bounds__(256) void conv_all(
    const float* __restrict__ x, const float* __restrict__ qw,
    const float* __restrict__ kw, const float* __restrict__ vw,
    const float* __restrict__ ow,
    short* __restrict__ x16, short* __restrict__ wb16, short* __restrict__ ow16)
{
    int i = blockIdx.x * 256 + threadIdx.x;   // float4 index, total 1703936
    const float* src; short* dst; int j;
    if (i < 1048576)      { src = x;  dst = x16;            j = i; }
    else if (i < 1310720) { src = qw; dst = wb16;           j = i - 1048576; }
    else if (i < 1376256) { src = kw; dst = wb16 + 1048576; j = i - 1310720; }
    else if (i < 1441792) { src = vw; dst = wb16 + 1310720; j = i - 1376256; }
    else                  { src = ow; dst = ow16;           j = i - 1441792; }
    float4 v = ((const float4*)src)[j];
    short4 o;
    o.x = f2bf(v.x); o.y = f2bf(v.y); o.z = f2bf(v.z); o.w = f2bf(v.w);
    ((short4*)dst)[j] = o;
}

// ---------------- bf16 MFMA GEMM (m97 structure, swizzled LDS): C = A * B^T ----------------
__global__ __launch_bounds__(256) void gemm_mfma(
    const short* __restrict__ A, const short* __restrict__ Bmat,
    const float* __restrict__ ve, float* __restrict__ C, int ldc)
{
    __shared__ short As[128*32];
    __shared__ short Bs[128*32];
    int tid = threadIdx.x;
    int w = tid >> 6, lane = tid & 63;
    int quad = lane >> 4, lc = lane & 15;
    int wy = w >> 1, wx = w & 1;
    int m0 = blockIdx.y * 128, n0 = blockIdx.x * 128;

    f32x4 acc[4][4];
    #pragma unroll
    for (int i = 0; i < 4; i++)
        #pragma unroll
        for (int j = 0; j < 4; j++) acc[i][j] = (f32x4){0.f,0.f,0.f,0.f};

    for (int k0 = 0; k0 < 1024; k0 += 32) {
        __syncthreads();
        #pragma unroll
        for (int i = 0; i < 2; i++) {
            int off = w*2048 + i*1024;            // byte offset (wave-uniform)
            int g = (off >> 4) + lane;            // 16B chunk idx
            int row = g >> 2, c = g & 3;
            int cg = c ^ (row & 3);               // XOR swizzle
            const short* ga = A + (size_t)(m0 + row)*1024 + k0 + cg*8;
            __builtin_amdgcn_global_load_lds(
                (const __attribute__((address_space(1))) void*)ga,
                (__attribute__((address_space(3))) void*)((char*)As + off), 16, 0, 0);
            const short* gb = Bmat + (size_t)(n0 + row)*1024 + k0 + cg*8;
            __builtin_amdgcn_global_load_lds(
                (const __attribute__((address_space(1))) void*)gb,
                (__attribute__((address_space(3))) void*)((char*)Bs + off), 16, 0, 0);
        }
        __syncthreads();

        bf16x8 af[4], bfr[4];
        #pragma unroll
        for (int tm = 0; tm < 4; tm++) {
            int row = wy*64 + tm*16 + lc;
            af[tm] = *(const bf16x8*)(As + row*32 + ((quad*8) ^ ((row&3)*8)));
        }
        #pragma unroll
        for (int tn = 0; tn < 4; tn++) {
            int row = wx*64 + tn*16 + lc;
            bfr[tn] = *(const bf16x8*)(Bs + row*32 + ((quad*8) ^ ((row&3)*8)));
        }
        #pragma unroll
        for (int tm = 0; tm < 4; tm++)
            #pragma unroll
            for (int tn = 0; tn < 4; tn++)
                acc[tm][tn] = __builtin_amdgcn_mfma_f32_16x16x32_bf16(af[tm], bfr[tn], acc[tm][tn], 0, 0, 0);
    }

    #pragma unroll
    for (int tm = 0; tm < 4; tm++)
        #pragma unroll
        for (int r = 0; r < 4; r++) {
            int m = m0 + wy*64 + tm*16 + quad*4 + r;
            #pragma unroll
            for (int tn = 0; tn < 4; tn++) {
                int n = n0 + wx*64 + tn*16 + lc;
                float v = acc[tm][tn][r];
                if (ve && n >= 1280) v += ve[(size_t)m*256 + (n - 1280)];
                C[(size_t)m*ldc + n] = v;
            }
        }
}

// ---------------- epilogue: RMSNorm + RoPE + gain*scale (q,k) -> bf16; v mix -> bf16 ----------------
__global__ __launch_bounds__(256) void qkv_epilogue(
    const float* __restrict__ qkv, const float* __restrict__ v0,
    const float* __restrict__ q_gain, const float* __restrict__ vr_lambda,
    short* __restrict__ qbh, short* __restrict__ kbh, short* __restrict__ vb,
    float* __restrict__ rawv)
{
    int wave = blockIdx.x * 4 + (threadIdx.x >> 6);
    int lane = threadIdx.x & 63;
    int row = wave / 24;     // 0..4095  (b*T + t)
    int hh  = wave % 24;
    int b = row >> 11;
    int t = row & (TT - 1);

    if (hh < 20) {
        int col = (hh < 16) ? (hh*64 + lane) : (1024 + (hh-16)*64 + lane);
        float val = qkv[(size_t)row*1536 + col];
        float ss = val * val;
        #pragma unroll
        for (int off = 32; off; off >>= 1) ss += __shfl_xor(ss, off);
        val *= rsqrtf(ss * (1.0f/64.0f) + EPSF);
        float partner = __shfl(val, lane ^ 32);
        int idx = lane & 31;
        float inv = (float)exp2((double)idx * (-LOG2_NB / 32.0));
        float fr = (float)t * inv;
        float sn, cs;
        sincosf(fr, &sn, &cs);
        float outv = (lane < 32) ? (val*cs + partner*sn) : (val*cs - partner*sn);
        if (hh < 16) {
            outv *= q_gain[hh] * SCALE_LOG2E;    // fold softmax scale+log2e into q
            qbh[(((size_t)(b*16 + hh))*2048 + t)*64 + lane] = f2bf(outv);
        } else {
            kbh[(((size_t)(b*4 + (hh-16)))*2048 + t)*64 + lane] = f2bf(outv);
        }
    } else {
        int vh = hh - 20;
        size_t off = ((size_t)row*4 + vh)*64 + lane;
        float vraw = qkv[(size_t)row*1536 + 1280 + vh*64 + lane];
        rawv[off] = vraw;
        float vmix = vr_lambda[0]*v0[off] + vr_lambda[1]*vraw;
        vb[off] = f2bf(vmix);                    // coalesced [b][t][kvh][d]
    }
}

// ---------------- V transpose: vb [b][t][kvh][d] -> vtb [b*4+kvh][d][t] ----------------
__global__ __launch_bounds__(256) void transpose_v(
    const short* __restrict__ vb, short* __restrict__ vtb)
{
    __shared__ short tile[64][72];
    int bk = blockIdx.x;           // b*4+kvh
    int tt = blockIdx.y;           // t tile (64)
    int b = bk >> 2, kvh = bk & 3;
    int tid = threadIdx.x;
    int t4 = tid >> 4;             // 0..15
    int d4 = (tid & 15) * 4;       // 0..60
    #pragma unroll
    for (int i = 0; i < 4; i++) {
        int t = t4 + i*16;
        const short* src = vb + (((size_t)(b*2048 + tt*64 + t)*4 + kvh)*64 + d4);
        *(short4*)&tile[t][d4] = *(const short4*)src;
    }
    __syncthreads();
    #pragma unroll
    for (int i = 0; i < 4; i++) {
        int d = t4 + i*16;
        int t0 = d4;
        short4 o;
        o.x = tile[t0+0][d]; o.y = tile[t0+1][d];
        o.z = tile[t0+2][d]; o.w = tile[t0+3][d];
        *(short4*)&vtb[((size_t)(bk*64 + d))*2048 + tt*64 + t0] = o;
    }
}

// ---------------- gate: sigmoid(x @ gate_w.T + gate_b) ----------------
__global__ __launch_bounds__(256) void gate_kernel(
    const float* __restrict__ x, const float* __restrict__ gw,
    const float* __restrict__ gb, float* __restrict__ gate)
{
    __shared__ float xs[1024];
    int row = blockIdx.x;
    int tid = threadIdx.x;
    *(float4*)&xs[tid*4] = *(const float4*)&x[(size_t)row*1024 + tid*4];
    __syncthreads();
    int wave = tid >> 6, lane = tid & 63;
    for (int h = wave; h < 16; h += 4) {
        const float* w = gw + (size_t)h * 1024;
        float s = 0.f;
        #pragma unroll
        for (int i = 0; i < 16; i++) s += xs[lane + 64*i] * w[lane + 64*i];
        #pragma unroll
        for (int off = 32; off; off >>= 1) s += __shfl_xor(s, off);
        if (lane == 0) gate[(size_t)row*16 + h] = 1.0f / (1.0f + __expf(-(s + gb[h])));
    }
}

// ---------------- MFMA flash attention: fixed-max softmax, 1 q-tile/block, dbuf, swizzled LDS ----------------
// Ps: 16 rows x 64 cols bf16 per wave, 16B-chunk XOR swizzle (chunk ^= row&7) -> 2KB/wave
__device__ inline void flash_step(
    const short* __restrict__ KsBuf, const short* __restrict__ VtBuf, short* __restrict__ ps,
    bf16x8 qf0, bf16x8 qf1,
    f32x4 (&o)[4], float (&l_lane)[4],
    int quad, int lc, int rowbase, bool diag)
{
    // S = Q K^T (exp2-domain scores: scale folded into Q)
    f32x4 s4[4];
    #pragma unroll
    for (int kn = 0; kn < 4; kn++) {
        int row = kn*16 + lc;
        const short* kr = KsBuf + row*64;
        int sw = (row & 7) * 8;
        bf16x8 kf0 = *(const bf16x8*)(kr + ((quad*8) ^ sw));
        bf16x8 kf1 = *(const bf16x8*)(kr + ((quad*8 + 32) ^ sw));
        f32x4 acc = (f32x4){0.f,0.f,0.f,0.f};
        acc = __builtin_amdgcn_mfma_f32_16x16x32_bf16(qf0, kf0, acc, 0, 0, 0);
        acc = __builtin_amdgcn_mfma_f32_16x16x32_bf16(qf1, kf1, acc, 0, 0, 0);
        s4[kn] = acc;
    }
    // p = exp2(s - FIXMAX); mask; accumulate l per-lane; write swizzled bf16 P
    #pragma unroll
    for (int kn = 0; kn < 4; kn++)
        #pragma unroll
        for (int r = 0; r < 4; r++) {
            float p = exp2f(s4[kn][r] - FIXMAX);
            if (diag && (kn*16 + lc > rowbase + quad*4 + r)) p = 0.f;
            l_lane[r] += p;
            int prow = quad*4 + r;
            int chunk = (kn*2 + (lc >> 3)) ^ (prow & 7);
            ps[prow*64 + chunk*8 + (lc & 7)] = f2bf(p);
        }
    __asm__ volatile("s_waitcnt lgkmcnt(0)" ::: "memory");
    int psw = lc & 7;
    bf16x8 pf0 = *(const bf16x8*)(ps + lc*64 + ((quad ^ psw) * 8));
    bf16x8 pf1 = *(const bf16x8*)(ps + lc*64 + (((quad + 4) ^ psw) * 8));

    #pragma unroll
    for (int dn = 0; dn < 4; dn++) {
        int row = dn*16 + lc;
        const short* vr = VtBuf + row*64;
        int sw = (row & 7) * 8;
        bf16x8 vf0 = *(const bf16x8*)(vr + ((quad*8) ^ sw));
        bf16x8 vf1 = *(const bf16x8*)(vr + ((quad*8 + 32) ^ sw));
        o[dn] = __builtin_amdgcn_mfma_f32_16x16x32_bf16(pf0, vf0, o[dn], 0, 0, 0);
        o[dn] = __builtin_amdgcn_mfma_f32_16x16x32_bf16(pf1, vf1, o[dn], 0, 0, 0);
    }
}

__global__ __launch_bounds__(256, 4) void flash_mfma(
    const short* __restrict__ qbh, const short* __restrict__ kbh,
    const short* __restrict__ vtb, const float* __restrict__ gate,
    short* __restrict__ y16)
{
    __shared__ short Ks[2][64*64];
    __shared__ short Vt[2][64*64];
    __shared__ short Ps[4][16*64];

    int bh = blockIdx.x;             // b*16 + h
    int b = bh >> 4, h = bh & 15, kvh = h >> 2;
    int qt = 31 - blockIdx.y;        // long blocks launch first (backfill-friendly)
    int tid = threadIdx.x;
    int w = tid >> 6, lane = tid & 63;
    int quad = lane >> 4, lc = lane & 15;

    const short* qbase = qbh + (((size_t)bh)*2048 + qt*64 + w*16 + lc)*64;
    bf16x8 qf0 = *(const bf16x8*)(qbase + quad*8);
    bf16x8 qf1 = *(const bf16x8*)(qbase + 32 + quad*8);

    f32x4 o[4];
    float l_lane[4];
    #pragma unroll
    for (int i = 0; i < 4; i++) { o[i] = (f32x4){0.f,0.f,0.f,0.f}; l_lane[i] = 0.f; }

    const size_t kbase = ((size_t)(b*4 + kvh))*2048*64;   // K [t][d]
    const size_t vbase = ((size_t)(b*4 + kvh))*64*2048;   // V^T [d][t]

    #define STAGE(buf, kt)                                                              \
    {                                                                                   \
        _Pragma("unroll")                                                               \
        for (int i = 0; i < 2; i++) {                                                   \
            int off = w*2048 + i*1024;                                                  \
            int g = (off >> 4) + lane;                                                  \
            int row = g >> 3, c = g & 7;                                                \
            int cg = c ^ (row & 7);                                                     \
            const short* gk = kbh + kbase + (size_t)((kt)*64 + row)*64 + cg*8;          \
            __builtin_amdgcn_global_load_lds(                                           \
                (const __attribute__((address_space(1))) void*)gk,                      \
                (__attribute__((address_space(3))) void*)((char*)Ks[buf] + off), 16, 0, 0); \
            const short* gv = vtb + vbase + (size_t)row*2048 + (kt)*64 + cg*8;          \
            __builtin_amdgcn_global_load_lds(                                           \
                (const __attribute__((address_space(1))) void*)gv,                      \
                (__attribute__((address_space(3))) void*)((char*)Vt[buf] + off), 16, 0, 0); \
        }                                                                               \
    }

    STAGE(0, 0);
    __syncthreads();

    for (int kt = 0; kt <= qt; kt++) {
        int cur = kt & 1;
        if (kt < qt) STAGE(cur ^ 1, kt + 1);
        flash_step(Ks[cur], Vt[cur], Ps[w], qf0, qf1, o, l_lane, quad, lc, w*16, kt == qt);
        __syncthreads();
    }

    // reduce l across the 16 cols (lc lanes within each quad)
    float l_r[4];
    #pragma unroll
    for (int r = 0; r < 4; r++) {
        float rs = l_lane[r];
        #pragma unroll
        for (int off = 1; off < 16; off <<= 1) rs += __shfl_xor(rs, off);
        l_r[r] = rs;
    }

    #pragma unroll
    for (int r = 0; r < 4; r++) {
        int row = b*2048 + qt*64 + w*16 + quad*4 + r;
        float g = gate[(size_t)row*16 + h] / l_r[r];
        #pragma unroll
        for (int dn = 0; dn < 4; dn++)
            y16[(size_t)row*1024 + h*64 + dn*16 + lc] = f2bf(o[dn][r] * g);
    }
}

extern "C" void kernel_launch(void* const* d_in, const int* in_sizes, int n_in,
                              void* d_out, int out_size, void* d_ws, size_t ws_size,
                              hipStream_t stream) {
    (void)in_sizes; (void)n_in; (void)out_size; (void)ws_size;
    const float* x  = (const float*)d_in[0];
    const float* qw = (const float*)d_in[1];
    const float* kw = (const float*)d_in[2];
    const float* vw = (const float*)d_in[3];
    const float* ow = (const float*)d_in[4];
    const float* ve = (const float*)d_in[5];
    const float* v0 = (const float*)d_in[6];
    const float* qg = (const float*)d_in[7];
    const float* vl = (const float*)d_in[8];
    const float* gw = (const float*)d_in[9];
    const float* gb = (const float*)d_in[10];

    float* out  = (float*)d_out;
    float* rawv = out + (size_t)BB*TT*DD;

    // workspace layout (float units)
    float* ws   = (float*)d_ws;
    float* qkv  = ws;                               // 4096*1536 f32; y16 reuses later
    float* p    = ws + 6291456;
    short* x16  = (short*)p;        p += 2097152;   // 4096*1024 bf16
    short* wb16 = (short*)p;        p += 786432;    // 1536*1024 bf16 (qw|kw|vw)
    short* ow16 = (short*)p;        p += 524288;    // 1024*1024 bf16
    short* qbh  = (short*)p;        p += 2097152;   // [b*16+h][t][d] bf16
    short* kbh  = (short*)p;        p += 524288;    // [b*4+kvh][t][d] bf16
    short* vtb  = (short*)p;        p += 524288;    // [b*4+kvh][d][t] bf16
    short* vb   = (short*)p;        p += 524288;    // [b][t][kvh][d] bf16 (pre-transpose)
    float* gt   = p;                                // 4096*16 f32
    short* y16  = (short*)qkv;

    conv_all<<<6656, 256, 0, stream>>>(x, qw, kw, vw, ow, x16, wb16, ow16);
    // QKV projection: M=4096, N=1536
    gemm_mfma<<<dim3(12, 32), 256, 0, stream>>>(x16, wb16, ve, qkv, 1536);
    qkv_epilogue<<<24576, 256, 0, stream>>>(qkv, v0, qg, vl, qbh, kbh, vb, rawv);
    transpose_v<<<dim3(8, 32), 256, 0, stream>>>(vb, vtb);
    gate_kernel<<<4096, 256, 0, stream>>>(x, gw, gb, gt);
    flash_mfma<<<dim3(32, 32), 256, 0, stream>>>(qbh, kbh, vtb, gt, y16);
    // out projection: M=4096, N=1024
    gemm_mfma<<<dim3(8, 32), 256, 0, stream>>>(y16, ow16, nullptr, out, 1024);
}

// Round 6
// 236.383 us; speedup vs baseline: 8.4497x; 1.0245x over previous
//
#include <hip/hip_runtime.h>
#include <math.h>

#define BB 2
#define TT 2048
#define DD 1024
#define NH 16
#define NKV 4
#define HD 64
#define EPSF 1.1920929e-07f
// T=2048 > TSL=1024 -> nb = 10000 * 2^(64/62); log2(nb) = log2(1e4) + 64/62
#define LOG2_NB 14.319970444065578
// 0.125 (1/sqrt(64)) * log2(e): folded into q so softmax runs in exp2 domain
#define SCALE_LOG2E 0.18033688011112042f
// fixed softmax max (exp2 units): |q.k| <= 8*8*1.5*0.125*log2e = 17.31 < 17.5
#define FIXMAX 17.5f

typedef __attribute__((ext_vector_type(8))) short bf16x8;
typedef __attribute__((ext_vector_type(4))) float f32x4;

__device__ inline short f2bf(float f) {
    unsigned u = __builtin_bit_cast(unsigned, f);
    unsigned r = (u + 0x7fffu + ((u >> 16) & 1u)) >> 16;
    return (short)r;
}

// ---------------- fused fp32 -> bf16 conversion for all 5 tensors ----------------
__global__ __launch_bounds__(256) void conv_all(
    const float* __restrict__ x, const float* __restrict__ qw,
    const float* __restrict__ kw, const float* __restrict__ vw,
    const float* __restrict__ ow,
    short* __restrict__ x16, short* __restrict__ wb16, short* __restrict__ ow16)
{
    int i = blockIdx.x * 256 + threadIdx.x;   // float4 index, total 1703936
    const float* src; short* dst; int j;
    if (i < 1048576)      { src = x;  dst = x16;            j = i; }
    else if (i < 1310720) { src = qw; dst = wb16;           j = i - 1048576; }
    else if (i < 1376256) { src = kw; dst = wb16 + 1048576; j = i - 1310720; }
    else if (i < 1441792) { src = vw; dst = wb16 + 1310720; j = i - 1376256; }
    else                  { src = ow; dst = ow16;           j = i - 1441792; }
    float4 v = ((const float4*)src)[j];
    short4 o;
    o.x = f2bf(v.x); o.y = f2bf(v.y); o.z = f2bf(v.z); o.w = f2bf(v.w);
    ((short4*)dst)[j] = o;
}

// ---------------- bf16 MFMA GEMM, split-K-in-block: C = A * B^T ----------------
// 512 threads = 8 waves. Waves 0-3: K[0,512) on 128x128 tile (2x2 of 64x64 each);
// waves 4-7: K[512,1024). Each half double-stages its own 16KB LDS pair.
// Partials reduced through 32KB LDS at the end; lower waves store C (+ve epilogue).
__global__ __launch_bounds__(512, 4) void gemm_mfma(
    const short* __restrict__ A, const short* __restrict__ Bmat,
    const float* __restrict__ ve, float* __restrict__ C, int ldc)
{
    __shared__ short As[2][128*32];
    __shared__ short Bs[2][128*32];
    __shared__ float Red[8192];            // 2 slots x 4096 floats
    int tid = threadIdx.x;
    int w8 = tid >> 6;                     // 0..7
    int half = w8 >> 2;                    // K-half
    int w = w8 & 3;                        // wave within half
    int lane = tid & 63;
    int quad = lane >> 4, lc = lane & 15;
    int wy = w >> 1, wx = w & 1;
    int m0 = blockIdx.y * 128, n0 = blockIdx.x * 128;

    f32x4 acc[4][4];
    #pragma unroll
    for (int i = 0; i < 4; i++)
        #pragma unroll
        for (int j = 0; j < 4; j++) acc[i][j] = (f32x4){0.f,0.f,0.f,0.f};

    short* myA = &As[half][0];
    short* myB = &Bs[half][0];
    int kbeg = half * 512;

    for (int ks = 0; ks < 512; ks += 32) {
        int k0 = kbeg + ks;
        __syncthreads();
        #pragma unroll
        for (int i = 0; i < 2; i++) {
            int off = w*2048 + i*1024;            // byte offset (wave-uniform)
            int g = (off >> 4) + lane;            // 16B chunk idx
            int row = g >> 2, c = g & 3;
            int cg = c ^ (row & 3);               // XOR swizzle
            const short* ga = A + (size_t)(m0 + row)*1024 + k0 + cg*8;
            __builtin_amdgcn_global_load_lds(
                (const __attribute__((address_space(1))) void*)ga,
                (__attribute__((address_space(3))) void*)((char*)myA + off), 16, 0, 0);
            const short* gb = Bmat + (size_t)(n0 + row)*1024 + k0 + cg*8;
            __builtin_amdgcn_global_load_lds(
                (const __attribute__((address_space(1))) void*)gb,
                (__attribute__((address_space(3))) void*)((char*)myB + off), 16, 0, 0);
        }
        __syncthreads();

        bf16x8 af[4], bfr[4];
        #pragma unroll
        for (int tm = 0; tm < 4; tm++) {
            int row = wy*64 + tm*16 + lc;
            af[tm] = *(const bf16x8*)(myA + row*32 + ((quad*8) ^ ((row&3)*8)));
        }
        #pragma unroll
        for (int tn = 0; tn < 4; tn++) {
            int row = wx*64 + tn*16 + lc;
            bfr[tn] = *(const bf16x8*)(myB + row*32 + ((quad*8) ^ ((row&3)*8)));
        }
        #pragma unroll
        for (int tm = 0; tm < 4; tm++)
            #pragma unroll
            for (int tn = 0; tn < 4; tn++)
                acc[tm][tn] = __builtin_amdgcn_mfma_f32_16x16x32_bf16(af[tm], bfr[tn], acc[tm][tn], 0, 0, 0);
    }

    // ---- reduce upper-half partials into lower-half accumulators via LDS ----
    // pairs: (0,4),(1,5) in round 0; (2,6),(3,7) in round 1. Slot = w&1.
    #pragma unroll
    for (int round = 0; round < 2; round++) {
        __syncthreads();
        if (half == 1 && (w >> 1) == round) {
            float* dst = Red + (w & 1) * 4096;
            #pragma unroll
            for (int tm = 0; tm < 4; tm++)
                #pragma unroll
                for (int tn = 0; tn < 4; tn++)
                    #pragma unroll
                    for (int r = 0; r < 4; r++)
                        dst[((tm*4 + tn)*4 + r)*64 + lane] = acc[tm][tn][r];
        }
        __syncthreads();
        if (half == 0 && (w >> 1) == round) {
            const float* src = Red + (w & 1) * 4096;
            #pragma unroll
            for (int tm = 0; tm < 4; tm++)
                #pragma unroll
                for (int tn = 0; tn < 4; tn++)
                    #pragma unroll
                    for (int r = 0; r < 4; r++)
                        acc[tm][tn][r] += src[((tm*4 + tn)*4 + r)*64 + lane];
        }
    }

    if (half == 0) {
        #pragma unroll
        for (int tm = 0; tm < 4; tm++)
            #pragma unroll
            for (int r = 0; r < 4; r++) {
                int m = m0 + wy*64 + tm*16 + quad*4 + r;
                #pragma unroll
                for (int tn = 0; tn < 4; tn++) {
                    int n = n0 + wx*64 + tn*16 + lc;
                    float v = acc[tm][tn][r];
                    if (ve && n >= 1280) v += ve[(size_t)m*256 + (n - 1280)];
                    C[(size_t)m*ldc + n] = v;
                }
            }
    }
}

// ---------------- epilogue: RMSNorm + RoPE + gain*scale (q,k) -> bf16; v mix -> bf16 ----------------
__global__ __launch_bounds__(256) void qkv_epilogue(
    const float* __restrict__ qkv, const float* __restrict__ v0,
    const float* __restrict__ q_gain, const float* __restrict__ vr_lambda,
    short* __restrict__ qbh, short* __restrict__ kbh, short* __restrict__ vb,
    float* __restrict__ rawv)
{
    int wave = blockIdx.x * 4 + (threadIdx.x >> 6);
    int lane = threadIdx.x & 63;
    int row = wave / 24;     // 0..4095  (b*T + t)
    int hh  = wave % 24;
    int b = row >> 11;
    int t = row & (TT - 1);

    if (hh < 20) {
        int col = (hh < 16) ? (hh*64 + lane) : (1024 + (hh-16)*64 + lane);
        float val = qkv[(size_t)row*1536 + col];
        float ss = val * val;
        #pragma unroll
        for (int off = 32; off; off >>= 1) ss += __shfl_xor(ss, off);
        val *= rsqrtf(ss * (1.0f/64.0f) + EPSF);
        float partner = __shfl(val, lane ^ 32);
        int idx = lane & 31;
        float inv = (float)exp2((double)idx * (-LOG2_NB / 32.0));
        float fr = (float)t * inv;
        float sn, cs;
        sincosf(fr, &sn, &cs);
        float outv = (lane < 32) ? (val*cs + partner*sn) : (val*cs - partner*sn);
        if (hh < 16) {
            outv *= q_gain[hh] * SCALE_LOG2E;    // fold softmax scale+log2e into q
            qbh[(((size_t)(b*16 + hh))*2048 + t)*64 + lane] = f2bf(outv);
        } else {
            kbh[(((size_t)(b*4 + (hh-16)))*2048 + t)*64 + lane] = f2bf(outv);
        }
    } else {
        int vh = hh - 20;
        size_t off = ((size_t)row*4 + vh)*64 + lane;
        float vraw = qkv[(size_t)row*1536 + 1280 + vh*64 + lane];
        rawv[off] = vraw;
        float vmix = vr_lambda[0]*v0[off] + vr_lambda[1]*vraw;
        vb[off] = f2bf(vmix);                    // coalesced [b][t][kvh][d]
    }
}

// ---------------- V transpose: vb [b][t][kvh][d] -> vtb [b*4+kvh][d][t] ----------------
__global__ __launch_bounds__(256) void transpose_v(
    const short* __restrict__ vb, short* __restrict__ vtb)
{
    __shared__ short tile[64][72];
    int bk = blockIdx.x;           // b*4+kvh
    int tt = blockIdx.y;           // t tile (64)
    int b = bk >> 2, kvh = bk & 3;
    int tid = threadIdx.x;
    int t4 = tid >> 4;             // 0..15
    int d4 = (tid & 15) * 4;       // 0..60
    #pragma unroll
    for (int i = 0; i < 4; i++) {
        int t = t4 + i*16;
        const short* src = vb + (((size_t)(b*2048 + tt*64 + t)*4 + kvh)*64 + d4);
        *(short4*)&tile[t][d4] = *(const short4*)src;
    }
    __syncthreads();
    #pragma unroll
    for (int i = 0; i < 4; i++) {
        int d = t4 + i*16;
        int t0 = d4;
        short4 o;
        o.x = tile[t0+0][d]; o.y = tile[t0+1][d];
        o.z = tile[t0+2][d]; o.w = tile[t0+3][d];
        *(short4*)&vtb[((size_t)(bk*64 + d))*2048 + tt*64 + t0] = o;
    }
}

// ---------------- gate: sigmoid(x @ gate_w.T + gate_b) ----------------
__global__ __launch_bounds__(256) void gate_kernel(
    const float* __restrict__ x, const float* __restrict__ gw,
    const float* __restrict__ gb, float* __restrict__ gate)
{
    __shared__ float xs[1024];
    int row = blockIdx.x;
    int tid = threadIdx.x;
    *(float4*)&xs[tid*4] = *(const float4*)&x[(size_t)row*1024 + tid*4];
    __syncthreads();
    int wave = tid >> 6, lane = tid & 63;
    for (int h = wave; h < 16; h += 4) {
        const float* w = gw + (size_t)h * 1024;
        float s = 0.f;
        #pragma unroll
        for (int i = 0; i < 16; i++) s += xs[lane + 64*i] * w[lane + 64*i];
        #pragma unroll
        for (int off = 32; off; off >>= 1) s += __shfl_xor(s, off);
        if (lane == 0) gate[(size_t)row*16 + h] = 1.0f / (1.0f + __expf(-(s + gb[h])));
    }
}

// ---------------- MFMA flash attention: fixed-max softmax, 1 q-tile/block, dbuf, swizzled LDS ----------------
__device__ inline void flash_step(
    const short* __restrict__ KsBuf, const short* __restrict__ VtBuf, short* __restrict__ ps,
    bf16x8 qf0, bf16x8 qf1,
    f32x4 (&o)[4], float (&l_lane)[4],
    int quad, int lc, int rowbase, bool diag)
{
    // S = Q K^T (exp2-domain scores: scale folded into Q)
    f32x4 s4[4];
    #pragma unroll
    for (int kn = 0; kn < 4; kn++) {
        int row = kn*16 + lc;
        const short* kr = KsBuf + row*64;
        int sw = (row & 7) * 8;
        bf16x8 kf0 = *(const bf16x8*)(kr + ((quad*8) ^ sw));
        bf16x8 kf1 = *(const bf16x8*)(kr + ((quad*8 + 32) ^ sw));
        f32x4 acc = (f32x4){0.f,0.f,0.f,0.f};
        acc = __builtin_amdgcn_mfma_f32_16x16x32_bf16(qf0, kf0, acc, 0, 0, 0);
        acc = __builtin_amdgcn_mfma_f32_16x16x32_bf16(qf1, kf1, acc, 0, 0, 0);
        s4[kn] = acc;
    }
    // p = exp2(s - FIXMAX); mask; accumulate l per-lane; write swizzled bf16 P
    #pragma unroll
    for (int kn = 0; kn < 4; kn++)
        #pragma unroll
        for (int r = 0; r < 4; r++) {
            float p = exp2f(s4[kn][r] - FIXMAX);
            if (diag && (kn*16 + lc > rowbase + quad*4 + r)) p = 0.f;
            l_lane[r] += p;
            int prow = quad*4 + r;
            int chunk = (kn*2 + (lc >> 3)) ^ (prow & 7);
            ps[prow*64 + chunk*8 + (lc & 7)] = f2bf(p);
        }
    __asm__ volatile("s_waitcnt lgkmcnt(0)" ::: "memory");
    int psw = lc & 7;
    bf16x8 pf0 = *(const bf16x8*)(ps + lc*64 + ((quad ^ psw) * 8));
    bf16x8 pf1 = *(const bf16x8*)(ps + lc*64 + (((quad + 4) ^ psw) * 8));

    #pragma unroll
    for (int dn = 0; dn < 4; dn++) {
        int row = dn*16 + lc;
        const short* vr = VtBuf + row*64;
        int sw = (row & 7) * 8;
        bf16x8 vf0 = *(const bf16x8*)(vr + ((quad*8) ^ sw));
        bf16x8 vf1 = *(const bf16x8*)(vr + ((quad*8 + 32) ^ sw));
        o[dn] = __builtin_amdgcn_mfma_f32_16x16x32_bf16(pf0, vf0, o[dn], 0, 0, 0);
        o[dn] = __builtin_amdgcn_mfma_f32_16x16x32_bf16(pf1, vf1, o[dn], 0, 0, 0);
    }
}

__global__ __launch_bounds__(256, 4) void flash_mfma(
    const short* __restrict__ qbh, const short* __restrict__ kbh,
    const short* __restrict__ vtb, const float* __restrict__ gate,
    short* __restrict__ y16)
{
    __shared__ short Ks[2][64*64];
    __shared__ short Vt[2][64*64];
    __shared__ short Ps[4][16*64];

    int bh = blockIdx.x;             // b*16 + h
    int b = bh >> 4, h = bh & 15, kvh = h >> 2;
    int qt = 31 - blockIdx.y;        // long blocks launch first (backfill-friendly)
    int tid = threadIdx.x;
    int w = tid >> 6, lane = tid & 63;
    int quad = lane >> 4, lc = lane & 15;

    const short* qbase = qbh + (((size_t)bh)*2048 + qt*64 + w*16 + lc)*64;
    bf16x8 qf0 = *(const bf16x8*)(qbase + quad*8);
    bf16x8 qf1 = *(const bf16x8*)(qbase + 32 + quad*8);

    f32x4 o[4];
    float l_lane[4];
    #pragma unroll
    for (int i = 0; i < 4; i++) { o[i] = (f32x4){0.f,0.f,0.f,0.f}; l_lane[i] = 0.f; }

    const size_t kbase = ((size_t)(b*4 + kvh))*2048*64;   // K [t][d]
    const size_t vbase = ((size_t)(b*4 + kvh))*64*2048;   // V^T [d][t]

    #define STAGE(buf, kt)                                                              \
    {                                                                                   \
        _Pragma("unroll")                                                               \
        for (int i = 0; i < 2; i++) {                                                   \
            int off = w*2048 + i*1024;                                                  \
            int g = (off >> 4) + lane;                                                  \
            int row = g >> 3, c = g & 7;                                                \
            int cg = c ^ (row & 7);                                                     \
            const short* gk = kbh + kbase + (size_t)((kt)*64 + row)*64 + cg*8;          \
            __builtin_amdgcn_global_load_lds(                                           \
                (const __attribute__((address_space(1))) void*)gk,                      \
                (__attribute__((address_space(3))) void*)((char*)Ks[buf] + off), 16, 0, 0); \
            const short* gv = vtb + vbase + (size_t)row*2048 + (kt)*64 + cg*8;          \
            __builtin_amdgcn_global_load_lds(                                           \
                (const __attribute__((address_space(1))) void*)gv,                      \
                (__attribute__((address_space(3))) void*)((char*)Vt[buf] + off), 16, 0, 0); \
        }                                                                               \
    }

    STAGE(0, 0);
    __syncthreads();

    for (int kt = 0; kt <= qt; kt++) {
        int cur = kt & 1;
        if (kt < qt) STAGE(cur ^ 1, kt + 1);
        flash_step(Ks[cur], Vt[cur], Ps[w], qf0, qf1, o, l_lane, quad, lc, w*16, kt == qt);
        __syncthreads();
    }

    // reduce l across the 16 cols (lc lanes within each quad)
    float l_r[4];
    #pragma unroll
    for (int r = 0; r < 4; r++) {
        float rs = l_lane[r];
        #pragma unroll
        for (int off = 1; off < 16; off <<= 1) rs += __shfl_xor(rs, off);
        l_r[r] = rs;
    }

    #pragma unroll
    for (int r = 0; r < 4; r++) {
        int row = b*2048 + qt*64 + w*16 + quad*4 + r;
        float g = gate[(size_t)row*16 + h] / l_r[r];
        #pragma unroll
        for (int dn = 0; dn < 4; dn++)
            y16[(size_t)row*1024 + h*64 + dn*16 + lc] = f2bf(o[dn][r] * g);
    }
}

extern "C" void kernel_launch(void* const* d_in, const int* in_sizes, int n_in,
                              void* d_out, int out_size, void* d_ws, size_t ws_size,
                              hipStream_t stream) {
    (void)in_sizes; (void)n_in; (void)out_size; (void)ws_size;
    const float* x  = (const float*)d_in[0];
    const float* qw = (const float*)d_in[1];
    const float* kw = (const float*)d_in[2];
    const float* vw = (const float*)d_in[3];
    const float* ow = (const float*)d_in[4];
    const float* ve = (const float*)d_in[5];
    const float* v0 = (const float*)d_in[6];
    const float* qg = (const float*)d_in[7];
    const float* vl = (const float*)d_in[8];
    const float* gw = (const float*)d_in[9];
    const float* gb = (const float*)d_in[10];

    float* out  = (float*)d_out;
    float* rawv = out + (size_t)BB*TT*DD;

    // workspace layout (float units)
    float* ws   = (float*)d_ws;
    float* qkv  = ws;                               // 4096*1536 f32; y16 reuses later
    float* p    = ws + 6291456;
    short* x16  = (short*)p;        p += 2097152;   // 4096*1024 bf16
    short* wb16 = (short*)p;        p += 786432;    // 1536*1024 bf16 (qw|kw|vw)
    short* ow16 = (short*)p;        p += 524288;    // 1024*1024 bf16
    short* qbh  = (short*)p;        p += 2097152;   // [b*16+h][t][d] bf16
    short* kbh  = (short*)p;        p += 524288;    // [b*4+kvh][t][d] bf16
    short* vtb  = (short*)p;        p += 524288;    // [b*4+kvh][d][t] bf16
    short* vb   = (short*)p;        p += 524288;    // [b][t][kvh][d] bf16 (pre-transpose)
    float* gt   = p;                                // 4096*16 f32
    short* y16  = (short*)qkv;

    conv_all<<<6656, 256, 0, stream>>>(x, qw, kw, vw, ow, x16, wb16, ow16);
    // QKV projection: M=4096, N=1536
    gemm_mfma<<<dim3(12, 32), 512, 0, stream>>>(x16, wb16, ve, qkv, 1536);
    qkv_epilogue<<<24576, 256, 0, stream>>>(qkv, v0, qg, vl, qbh, kbh, vb, rawv);
    transpose_v<<<dim3(8, 32), 256, 0, stream>>>(vb, vtb);
    gate_kernel<<<4096, 256, 0, stream>>>(x, gw, gb, gt);
    flash_mfma<<<dim3(32, 32), 256, 0, stream>>>(qbh, kbh, vtb, gt, y16);
    // out projection: M=4096, N=1024
    gemm_mfma<<<dim3(8, 32), 512, 0, stream>>>(y16, ow16, nullptr, out, 1024);
}